// Round 7
// baseline (341.548 us; speedup 1.0000x reference)
//
#include <hip/hip_runtime.h>
#include <cstdint>

#define N_TOK 2048
#define CDIM  1024
#define NEXP  16
#define TOPK  2
#define HDIM  1024
#define SDIM  2048
#define ESLOT 48
#define ESLOT64 80
#define GU_EXP_BLOCKS (ESLOT * 16)              // 768
#define GU_SH_BLOCKS  (16 * 32)                 // 512
#define GU_NWG (GU_EXP_BLOCKS + GU_SH_BLOCKS)   // 1280
#define DN_EXP_BLOCKS (ESLOT64 * 8)             // 640
#define DN_SH_BLOCKS  (32 * 8)                  // 256
#define DN_NWG (DN_EXP_BLOCKS + DN_SH_BLOCKS)   // 896

typedef __bf16 bf16;
typedef __bf16 bf16x8 __attribute__((ext_vector_type(8)));
typedef float  f32x4  __attribute__((ext_vector_type(4)));
typedef unsigned int u32;
typedef unsigned short u16;

typedef __attribute__((address_space(3))) uint32_t lds_u32_t;
typedef __attribute__((address_space(1))) uint32_t glb_u32_t;

__device__ __forceinline__ void gload16(const void* g, void* l) {
  __builtin_amdgcn_global_load_lds((const glb_u32_t*)(uintptr_t)g,
                                   (lds_u32_t*)(uintptr_t)l, 16, 0, 0);
}
// un-killable async global load: volatile asm cannot be remat'd/sunk/cloned.
// NOTE: compiler does NOT track vmcnt for this — consumer must WAITVM() first.
__device__ __forceinline__ f32x4 gl4(const float* p) {
  f32x4 r;
  asm volatile("global_load_dwordx4 %0, %1, off" : "=v"(r) : "v"(p));
  return r;
}
#define WAITVM() do { asm volatile("s_waitcnt vmcnt(0)" ::: "memory"); \
                      __builtin_amdgcn_sched_barrier(0); } while (0)

__device__ __forceinline__ float fromb(u16 s) {
  union { float f; u32 u; } z; z.u = ((u32)s) << 16; return z.f;
}
__device__ __forceinline__ int xcd_swz(int bid, int nwg) {
  return (bid & 7) * (nwg >> 3) + (bid >> 3);
}

// ---------------- router ----------------
__global__ void init_counts_kernel(int* counts) {
  if (threadIdx.x < NEXP) counts[threadIdx.x] = 0;
}

__global__ void router_kernel(const float* __restrict__ x,
                              const float* __restrict__ rw,
                              int* __restrict__ sel,
                              float* __restrict__ gatew,
                              int* __restrict__ counts) {
  int n = blockIdx.x;
  int lane = threadIdx.x;
  const float* xr = x + (size_t)n * CDIM;
  float acc[NEXP];
#pragma unroll
  for (int e = 0; e < NEXP; ++e) acc[e] = 0.f;
  for (int i = lane; i < CDIM; i += 64) {
    float xi = xr[i];
#pragma unroll
    for (int e = 0; e < NEXP; ++e) acc[e] += xi * rw[e * CDIM + i];
  }
#pragma unroll
  for (int off = 32; off > 0; off >>= 1) {
#pragma unroll
    for (int e = 0; e < NEXP; ++e) acc[e] += __shfl_xor(acc[e], off, 64);
  }
  if (lane == 0) {
    int i0 = 0; float v0 = acc[0];
#pragma unroll
    for (int e = 1; e < NEXP; ++e) if (acc[e] > v0) { v0 = acc[e]; i0 = e; }
    int i1 = (i0 == 0) ? 1 : 0; float v1 = acc[i1];
#pragma unroll
    for (int e = 0; e < NEXP; ++e) if (e != i0 && acc[e] > v1) { v1 = acc[e]; i1 = e; }
    sel[2 * n] = i0; sel[2 * n + 1] = i1;
    gatew[2 * n]     = 1.f / (1.f + expf(-v0));
    gatew[2 * n + 1] = 1.f / (1.f + expf(-v1));
    atomicAdd(&counts[i0], 1);
    atomicAdd(&counts[i1], 1);
  }
}

__global__ void scan_kernel(const int* __restrict__ counts,
                            int* __restrict__ offsets,
                            int* __restrict__ cursor,
                            int* __restrict__ tab128,
                            int* __restrict__ tab64,
                            int* __restrict__ ntiles) {
  if (threadIdx.x == 0) {
    int s = 0, a = 0, b = 0;
    for (int e = 0; e < NEXP; ++e) {
      offsets[e] = s; cursor[e] = s;
      int c = counts[e];
      for (int m0 = 0; m0 < c; m0 += 128) tab128[a++] = (e << 16) | m0;
      for (int m0 = 0; m0 < c; m0 += 64)  tab64[b++]  = (e << 16) | m0;
      s += c;
    }
    ntiles[0] = a; ntiles[1] = b;
  }
}

__global__ void scatter_kernel(const int* __restrict__ sel,
                               const float* __restrict__ gatew,
                               int* __restrict__ cursor,
                               int* __restrict__ entry_token,
                               float* __restrict__ entry_gate,
                               int* __restrict__ entry_pos) {
  int t = blockIdx.x * blockDim.x + threadIdx.x;
  if (t >= N_TOK * TOPK) return;
  int e = sel[t];
  int pos = atomicAdd(&cursor[e], 1);
  entry_token[pos] = t >> 1;
  entry_gate[pos] = gatew[t];
  entry_pos[t] = pos;
}

__global__ void convert_x_kernel(const float* __restrict__ x, bf16* __restrict__ xb) {
  int i = (blockIdx.x * 256 + threadIdx.x) * 8;
  float4 f0 = *(const float4*)(x + i);
  float4 f1 = *(const float4*)(x + i + 4);
  bf16x8 v;
  v[0]=(bf16)f0.x; v[1]=(bf16)f0.y; v[2]=(bf16)f0.z; v[3]=(bf16)f0.w;
  v[4]=(bf16)f1.x; v[5]=(bf16)f1.y; v[6]=(bf16)f1.z; v[7]=(bf16)f1.w;
  *(bf16x8*)(xb + i) = v;
}

// ================= GU: gate+up GEMM, expert+shared, asm-pinned pipeline ========
// Tile 128m x 64h (dual-B), BK=64, 4 waves each 64m x 32h.
__global__ __launch_bounds__(256, 3)
void gu4(const bf16* __restrict__ xb,
         const float* __restrict__ guw,
         const float* __restrict__ sgw,
         const float* __restrict__ suw,
         bf16* __restrict__ h_exp,
         bf16* __restrict__ h_sh,
         const int* __restrict__ counts,
         const int* __restrict__ offsets,
         const int* __restrict__ entry_token,
         const int* __restrict__ tab128,
         const int* __restrict__ ntiles) {
  __shared__ __align__(16) bf16 sA[2][128 * 64];
  __shared__ __align__(16) bf16 sBg[64 * 64];
  __shared__ __align__(16) bf16 sBu[64 * 64];
  __shared__ int rowtok[128];

  const int bid = xcd_swz(blockIdx.x, GU_NWG);
  const int t = threadIdx.x;
  const bool is_exp = bid < GU_EXP_BLOCKS;
  const int wid = t >> 6, lane = t & 63;

  int n0, mguard;
  bf16* hbase; int hstride;
  const float *Bgp, *Bup;

  if (is_exp) {
    const int slot = bid >> 4;
    if (slot >= ntiles[0]) return;
    const int packed = tab128[slot];
    const int e = packed >> 16;
    const int m0 = packed & 0xffff;
    const int cnt = counts[e];
    const int base = offsets[e];
    n0 = (bid & 15) * 64;
    mguard = cnt - m0;
    if (t < 128) {
      int r = m0 + t;
      rowtok[t] = entry_token[base + ((r < cnt) ? r : (cnt - 1))];
    }
    Bgp = guw + (size_t)e * CDIM * 2 * HDIM + n0;          // k-major, ldb=2048
    Bup = Bgp + HDIM;
    hbase = h_exp + (size_t)(base + m0) * HDIM + n0;
    hstride = HDIM;
  } else {
    const int sid = bid - GU_EXP_BLOCKS;
    const int m0 = (sid >> 5) * 128;
    n0 = (sid & 31) * 64;
    mguard = 128;
    if (t < 128) rowtok[t] = m0 + t;
    Bgp = sgw + (size_t)n0 * CDIM;                         // n-major, ldb=1024
    Bup = suw + (size_t)n0 * CDIM;
    hbase = h_sh + (size_t)m0 * SDIM + n0;
    hstride = SDIM;
  }
  __syncthreads();

  const bf16* asrc[4];
#pragma unroll
  for (int i = 0; i < 4; ++i) {
    const int row = i * 32 + (t >> 3);
    const int c = (t & 7) ^ (row & 7);
    asrc[i] = xb + (size_t)rowtok[row] * CDIM + c * 8;
  }
  const int adst = t * 8;

  const int th = t & 127;
  bf16* bdst = (t >= 128) ? sBu : sBg;
  const float* Bp = (t >= 128) ? Bup : Bgp;
  const int ek = th >> 4, ec4 = (th & 15) * 4;   // expert: k-chunk, col4
  const int srow = th >> 1, shalf = th & 1;      // shared: n-row, k-half

  f32x4 pf[8];

#define LOADB(k0_)                                                               \
  if (is_exp) {                                                                  \
    _Pragma("unroll")                                                            \
    for (int j = 0; j < 8; ++j)                                                  \
      pf[j] = gl4(Bp + (size_t)((k0_) + ek * 8 + j) * (2 * HDIM) + ec4);         \
  } else {                                                                       \
    _Pragma("unroll")                                                            \
    for (int j = 0; j < 8; ++j)                                                  \
      pf[j] = gl4(Bp + (size_t)srow * CDIM + (k0_) + shalf * 32 + j * 4);        \
  }

#define CVTB()                                                                   \
  if (is_exp) {                                                                  \
    _Pragma("unroll")                                                            \
    for (int n = 0; n < 4; ++n) {                                                \
      const int rb = ec4 + n; bf16x8 v;                                          \
      _Pragma("unroll")                                                          \
      for (int j = 0; j < 8; ++j) v[j] = (bf16)pf[j][n];                         \
      *(bf16x8*)&bdst[rb * 64 + ((ek ^ (rb & 7)) << 3)] = v;                     \
    }                                                                            \
  } else {                                                                       \
    _Pragma("unroll")                                                            \
    for (int q = 0; q < 4; ++q) {                                                \
      bf16x8 v;                                                                  \
      v[0]=(bf16)pf[2*q][0]; v[1]=(bf16)pf[2*q][1];                              \
      v[2]=(bf16)pf[2*q][2]; v[3]=(bf16)pf[2*q][3];                              \
      v[4]=(bf16)pf[2*q+1][0]; v[5]=(bf16)pf[2*q+1][1];                          \
      v[6]=(bf16)pf[2*q+1][2]; v[7]=(bf16)pf[2*q+1][3];                          \
      const int c = shalf * 4 + q;                                               \
      *(bf16x8*)&bdst[srow * 64 + ((c ^ (srow & 7)) << 3)] = v;                  \
    }                                                                            \
  }

  const int wr = (wid >> 1) * 64, wc = (wid & 1) * 32;
  const int lrow = lane & 15, grp = lane >> 4;

  f32x4 ag[4][2], au[4][2];
#pragma unroll
  for (int m = 0; m < 4; ++m)
#pragma unroll
    for (int n = 0; n < 2; ++n)
#pragma unroll
      for (int i = 0; i < 4; ++i) { ag[m][n][i] = 0.f; au[m][n][i] = 0.f; }

  // prologue
#pragma unroll
  for (int i = 0; i < 4; ++i) gload16(asrc[i], &sA[0][adst + i * 2048]);
  LOADB(0)
  WAITVM();
  CVTB()
  __syncthreads();

  int p = 0;
  for (int k0 = 0; k0 < CDIM; k0 += 64) {
    const int kn = k0 + 64;
    if (kn < CDIM) {
#pragma unroll
      for (int i = 0; i < 4; ++i) gload16(asrc[i] + kn, &sA[p ^ 1][adst + i * 2048]);
      LOADB(kn)
    }
#pragma unroll
    for (int ks = 0; ks < 2; ++ks) {
      const int ch = ks * 4 + grp;
      bf16x8 av[4], bg[2], bu[2];
#pragma unroll
      for (int m = 0; m < 4; ++m) {
        const int r = wr + m * 16 + lrow;
        av[m] = *(const bf16x8*)&sA[p][r * 64 + ((ch ^ (r & 7)) << 3)];
      }
#pragma unroll
      for (int n = 0; n < 2; ++n) {
        const int r = wc + n * 16 + lrow;
        bg[n] = *(const bf16x8*)&sBg[r * 64 + ((ch ^ (r & 7)) << 3)];
        bu[n] = *(const bf16x8*)&sBu[r * 64 + ((ch ^ (r & 7)) << 3)];
      }
#pragma unroll
      for (int m = 0; m < 4; ++m)
#pragma unroll
        for (int n = 0; n < 2; ++n) {
          ag[m][n] = __builtin_amdgcn_mfma_f32_16x16x32_bf16(av[m], bg[n], ag[m][n], 0, 0, 0);
          au[m][n] = __builtin_amdgcn_mfma_f32_16x16x32_bf16(av[m], bu[n], au[m][n], 0, 0, 0);
        }
    }
    __syncthreads();              // waves done reading sBg/sBu
    if (kn < CDIM) {
      WAITVM();                   // pf landed (had full MFMA phase in flight)
      CVTB()
      __syncthreads();            // next sB + sA[p^1] ready
      p ^= 1;
    }
  }

#pragma unroll
  for (int m = 0; m < 4; ++m) {
#pragma unroll
    for (int i = 0; i < 4; ++i) {
      const int rl = wr + m * 16 + grp * 4 + i;
      if (rl >= mguard) continue;
      bf16* orow = hbase + (size_t)rl * hstride;
#pragma unroll
      for (int n = 0; n < 2; ++n) {
        const float g = ag[m][n][i];
        const float u = au[m][n][i];
        orow[wc + n * 16 + lrow] = (bf16)(g * u * __builtin_amdgcn_rcpf(1.f + __expf(-g)));
      }
    }
  }
#undef LOADB
#undef CVTB
}

// ================= DOWN GEMM, expert+shared, asm-pinned pipeline ==============
// Tile 64m x 128n, BK=64, 4 waves each 32m x 64n.
__global__ __launch_bounds__(256, 4)
void dn4(const bf16* __restrict__ h_exp,
         const bf16* __restrict__ h_sh,
         const float* __restrict__ dw,
         const float* __restrict__ sdw,
         const float* __restrict__ entry_gate,
         bf16* __restrict__ out_e,
         float* __restrict__ out,
         const int* __restrict__ counts,
         const int* __restrict__ offsets,
         const int* __restrict__ tab64,
         const int* __restrict__ ntiles) {
  __shared__ __align__(16) bf16 sA[2][64 * 64];
  __shared__ __align__(16) bf16 sB[128 * 64];

  const int bid = xcd_swz(blockIdx.x, DN_NWG);
  const int t = threadIdx.x;
  const bool is_exp = bid < DN_EXP_BLOCKS;
  const int wid = t >> 6, lane = t & 63;

  int n0, mguard, K, rowbase;
  const bf16* Ab;
  const float* Bp;

  if (is_exp) {
    const int slot = bid >> 3;
    if (slot >= ntiles[1]) return;
    const int packed = tab64[slot];
    const int e = packed >> 16;
    const int m0 = packed & 0xffff;
    const int cnt = counts[e];
    n0 = (bid & 7) * 128;
    mguard = cnt - m0;
    K = HDIM;
    rowbase = offsets[e] + m0;
    Ab = h_exp;
    Bp = dw + (size_t)e * HDIM * CDIM + n0;    // k-major, ldb=1024
  } else {
    const int sid = bid - DN_EXP_BLOCKS;
    const int m0 = (sid >> 3) * 64;
    n0 = (sid & 7) * 128;
    mguard = 64;
    K = SDIM;
    rowbase = m0;
    Ab = h_sh;
    Bp = sdw;                                   // n-major, ldb=2048
  }

  const bf16* asrc[2];
#pragma unroll
  for (int i = 0; i < 2; ++i) {
    const int row = i * 32 + (t >> 3);
    const int c = (t & 7) ^ (row & 7);
    int rg = rowbase + row;
    if (is_exp && rg > N_TOK * TOPK - 1) rg = N_TOK * TOPK - 1;
    asrc[i] = Ab + (size_t)rg * K + c * 8;
  }
  const int adst = t * 8;

  const int ek = t >> 5, ec4 = (t & 31) * 4;   // expert: k-chunk, col4 (128 cols)
  const int srow = t >> 1, shalf = t & 1;      // shared: n-row, k-half

  f32x4 pf[8];

#define LOADB(k0_)                                                                \
  if (is_exp) {                                                                   \
    _Pragma("unroll")                                                             \
    for (int j = 0; j < 8; ++j)                                                   \
      pf[j] = gl4(Bp + (size_t)((k0_) + ek * 8 + j) * CDIM + ec4);                \
  } else {                                                                        \
    _Pragma("unroll")                                                             \
    for (int j = 0; j < 8; ++j)                                                   \
      pf[j] = gl4(Bp + (size_t)(n0 + srow) * SDIM + (k0_) + shalf * 32 + j * 4);  \
  }

#define CVTB()                                                                    \
  if (is_exp) {                                                                   \
    _Pragma("unroll")                                                             \
    for (int n = 0; n < 4; ++n) {                                                 \
      const int rb = ec4 + n; bf16x8 v;                                           \
      _Pragma("unroll")                                                           \
      for (int j = 0; j < 8; ++j) v[j] = (bf16)pf[j][n];                          \
      *(bf16x8*)&sB[rb * 64 + ((ek ^ (rb & 7)) << 3)] = v;                        \
    }                                                                             \
  } else {                                                                        \
    _Pragma("unroll")                                                             \
    for (int q = 0; q < 4; ++q) {                                                 \
      bf16x8 v;                                                                   \
      v[0]=(bf16)pf[2*q][0]; v[1]=(bf16)pf[2*q][1];                               \
      v[2]=(bf16)pf[2*q][2]; v[3]=(bf16)pf[2*q][3];                               \
      v[4]=(bf16)pf[2*q+1][0]; v[5]=(bf16)pf[2*q+1][1];                           \
      v[6]=(bf16)pf[2*q+1][2]; v[7]=(bf16)pf[2*q+1][3];                           \
      const int c = shalf * 4 + q;                                                \
      *(bf16x8*)&sB[srow * 64 + ((c ^ (srow & 7)) << 3)] = v;                     \
    }                                                                             \
  }

  const int wr = (wid >> 1) * 32, wc = (wid & 1) * 64;
  const int lrow = lane & 15, grp = lane >> 4;

  f32x4 acc[2][4];
#pragma unroll
  for (int m = 0; m < 2; ++m)
#pragma unroll
    for (int n = 0; n < 4; ++n)
#pragma unroll
      for (int i = 0; i < 4; ++i) acc[m][n][i] = 0.f;

#pragma unroll
  for (int i = 0; i < 2; ++i) gload16(asrc[i], &sA[0][adst + i * 2048]);
  LOADB(0)
  WAITVM();
  CVTB()
  __syncthreads();

  int p = 0;
  for (int k0 = 0; k0 < K; k0 += 64) {
    const int kn = k0 + 64;
    if (kn < K) {
#pragma unroll
      for (int i = 0; i < 2; ++i) gload16(asrc[i] + kn, &sA[p ^ 1][adst + i * 2048]);
      LOADB(kn)
    }
#pragma unroll
    for (int ks = 0; ks < 2; ++ks) {
      const int ch = ks * 4 + grp;
      bf16x8 av[2], bv[4];
#pragma unroll
      for (int m = 0; m < 2; ++m) {
        const int r = wr + m * 16 + lrow;
        av[m] = *(const bf16x8*)&sA[p][r * 64 + ((ch ^ (r & 7)) << 3)];
      }
#pragma unroll
      for (int n = 0; n < 4; ++n) {
        const int r = wc + n * 16 + lrow;
        bv[n] = *(const bf16x8*)&sB[r * 64 + ((ch ^ (r & 7)) << 3)];
      }
#pragma unroll
      for (int m = 0; m < 2; ++m)
#pragma unroll
        for (int n = 0; n < 4; ++n)
          acc[m][n] = __builtin_amdgcn_mfma_f32_16x16x32_bf16(av[m], bv[n], acc[m][n], 0, 0, 0);
    }
    __syncthreads();
    if (kn < K) {
      WAITVM();
      CVTB()
      __syncthreads();
      p ^= 1;
    }
  }

#pragma unroll
  for (int m = 0; m < 2; ++m) {
#pragma unroll
    for (int i = 0; i < 4; ++i) {
      const int rl = wr + m * 16 + grp * 4 + i;
      if (rl >= mguard) continue;
      if (is_exp) {
        const int row = rowbase + rl;
        const float sc = entry_gate[row];
        bf16* orow = out_e + (size_t)row * CDIM + n0;
#pragma unroll
        for (int n = 0; n < 4; ++n)
          orow[wc + n * 16 + lrow] = (bf16)(acc[m][n][i] * sc);
      } else {
        float* orow = out + (size_t)(rowbase + rl) * CDIM + n0;
#pragma unroll
        for (int n = 0; n < 4; ++n)
          orow[wc + n * 16 + lrow] = acc[m][n][i];
      }
    }
  }
#undef LOADB
#undef CVTB
}

// ---------------- combine ----------------
__global__ void combine_kernel(float* __restrict__ out,
                               const bf16* __restrict__ out_e,
                               const int* __restrict__ entry_pos) {
  int tid = blockIdx.x * blockDim.x + threadIdx.x;
  int n = tid >> 8;
  int c4 = tid & 255;
  int p0 = entry_pos[2 * n];
  int p1 = entry_pos[2 * n + 1];
  float4 v = ((const float4*)out)[tid];
  ushort4 a = *(const ushort4*)((const u16*)out_e + (size_t)p0 * CDIM + c4 * 4);
  ushort4 b = *(const ushort4*)((const u16*)out_e + (size_t)p1 * CDIM + c4 * 4);
  v.x += fromb(a.x) + fromb(b.x);
  v.y += fromb(a.y) + fromb(b.y);
  v.z += fromb(a.z) + fromb(b.z);
  v.w += fromb(a.w) + fromb(b.w);
  ((float4*)out)[tid] = v;
}

extern "C" void kernel_launch(void* const* d_in, const int* in_sizes, int n_in,
                              void* d_out, int out_size, void* d_ws, size_t ws_size,
                              hipStream_t stream) {
  const float* x   = (const float*)d_in[0];
  const float* rw  = (const float*)d_in[1];
  const float* guw = (const float*)d_in[2];
  const float* dw  = (const float*)d_in[3];
  const float* sgw = (const float*)d_in[4];
  const float* suw = (const float*)d_in[5];
  const float* sdw = (const float*)d_in[6];
  float* out = (float*)d_out;
  char* ws = (char*)d_ws;

  int*   sel         = (int*)(ws + 0);
  float* gatew       = (float*)(ws + 16384);
  int*   counts      = (int*)(ws + 32768);
  int*   offsets     = (int*)(ws + 32832);
  int*   cursor      = (int*)(ws + 32896);
  int*   ntiles      = (int*)(ws + 32960);
  int*   tab128      = (int*)(ws + 33024);   // 48 ints
  int*   tab64       = (int*)(ws + 33280);   // 80 ints
  int*   entry_token = (int*)(ws + 33664);
  float* entry_gate  = (float*)(ws + 50048);
  int*   entry_pos   = (int*)(ws + 66432);
  bf16*  xb          = (bf16*)(ws + 82816);                       // 4 MB
  bf16*  h_exp       = (bf16*)(ws + 82816 + (size_t)4194304);     // 8 MB
  bf16*  h_sh        = (bf16*)(ws + 82816 + (size_t)12582912);    // 8 MB
  bf16*  out_e       = (bf16*)(ws + 82816 + (size_t)20971520);    // 8 MB

  convert_x_kernel<<<N_TOK * CDIM / 8 / 256, 256, 0, stream>>>(x, xb);
  init_counts_kernel<<<1, 64, 0, stream>>>(counts);
  router_kernel<<<N_TOK, 64, 0, stream>>>(x, rw, sel, gatew, counts);
  scan_kernel<<<1, 64, 0, stream>>>(counts, offsets, cursor, tab128, tab64, ntiles);
  scatter_kernel<<<16, 256, 0, stream>>>(sel, gatew, cursor, entry_token, entry_gate, entry_pos);

  gu4<<<GU_NWG, 256, 0, stream>>>(xb, guw, sgw, suw, h_exp, h_sh,
                                  counts, offsets, entry_token, tab128, ntiles);

  dn4<<<DN_NWG, 256, 0, stream>>>(h_exp, h_sh, dw, sdw, entry_gate, out_e, out,
                                  counts, offsets, tab64, ntiles);

  combine_kernel<<<(N_TOK * CDIM / 4) / 256, 256, 0, stream>>>(out, out_e, entry_pos);
}

// Round 8
// 240.581 us; speedup vs baseline: 1.4197x; 1.4197x over previous
//
#include <hip/hip_runtime.h>
#include <cstdint>

#define N_TOK 2048
#define CDIM  1024
#define NEXP  16
#define TOPK  2
#define HDIM  1024
#define SDIM  2048
#define ESLOT 48
#define ESLOT64 80
#define GU_EXP_BLOCKS (ESLOT * 16)              // 768
#define GU_SH_BLOCKS  (16 * 32)                 // 512
#define GU_NWG (GU_EXP_BLOCKS + GU_SH_BLOCKS)   // 1280
#define DN_EXP_BLOCKS (ESLOT64 * 8)             // 640
#define DN_SH_BLOCKS  (32 * 8)                  // 256
#define DN_NWG (DN_EXP_BLOCKS + DN_SH_BLOCKS)   // 896

typedef __bf16 bf16;
typedef __bf16 bf16x8 __attribute__((ext_vector_type(8)));
typedef float  f32x4  __attribute__((ext_vector_type(4)));
typedef unsigned int u32;
typedef unsigned short u16;

typedef __attribute__((address_space(3))) uint32_t lds_u32_t;
typedef __attribute__((address_space(1))) uint32_t glb_u32_t;

__device__ __forceinline__ void gload16(const void* g, void* l) {
  __builtin_amdgcn_global_load_lds((const glb_u32_t*)(uintptr_t)g,
                                   (lds_u32_t*)(uintptr_t)l, 16, 0, 0);
}
__device__ __forceinline__ float fromb(u16 s) {
  union { float f; u32 u; } z; z.u = ((u32)s) << 16; return z.f;
}
__device__ __forceinline__ int xcd_swz(int bid, int nwg) {
  return (bid & 7) * (nwg >> 3) + (bid >> 3);
}

// ---------------- weight/activation canonicalization ----------------
// plain fp32 -> bf16 (2,097,152 elements per call; grid 1024 x 256 x 8)
__global__ void convert_plain(const float* __restrict__ s, bf16* __restrict__ d) {
  int i = (blockIdx.x * 256 + threadIdx.x) * 8;
  float4 f0 = *(const float4*)(s + i);
  float4 f1 = *(const float4*)(s + i + 4);
  bf16x8 v;
  v[0]=(bf16)f0.x; v[1]=(bf16)f0.y; v[2]=(bf16)f0.z; v[3]=(bf16)f0.w;
  v[4]=(bf16)f1.x; v[5]=(bf16)f1.y; v[6]=(bf16)f1.z; v[7]=(bf16)f1.w;
  *(bf16x8*)(d + i) = v;
}

// transpose-convert: src [E][K][N] fp32 -> dst [E][N][K] bf16 (64x64 tiles)
__global__ __launch_bounds__(256)
void convert_t(const float* __restrict__ src, bf16* __restrict__ dst, int K, int N) {
  __shared__ float ld[64 * 68];
  const int e = blockIdx.z;
  const int n0 = blockIdx.x * 64, k0 = blockIdx.y * 64;
  const float* s = src + (size_t)e * K * N;
  bf16* d = dst + (size_t)e * N * K;
  const int t = threadIdx.x;
  const int kk = t >> 4, c4 = (t & 15) * 4;
#pragma unroll
  for (int q = 0; q < 4; ++q) {
    float4 f = *(const float4*)(s + (size_t)(k0 + kk + q * 16) * N + n0 + c4);
    float* lp = &ld[(kk + q * 16) * 68 + c4];
    lp[0] = f.x; lp[1] = f.y; lp[2] = f.z; lp[3] = f.w;
  }
  __syncthreads();
  const int nn = t >> 2, kc = (t & 3) * 16;
  bf16x8 v0, v1;
#pragma unroll
  for (int j = 0; j < 8; ++j) {
    v0[j] = (bf16)ld[(kc + j) * 68 + nn];
    v1[j] = (bf16)ld[(kc + 8 + j) * 68 + nn];
  }
  bf16* dp = d + (size_t)(n0 + nn) * K + k0 + kc;
  *(bf16x8*)dp = v0;
  *(bf16x8*)(dp + 8) = v1;
}

// ---------------- router ----------------
__global__ void init_counts_kernel(int* counts) {
  if (threadIdx.x < NEXP) counts[threadIdx.x] = 0;
}

__global__ void router_kernel(const float* __restrict__ x,
                              const float* __restrict__ rw,
                              int* __restrict__ sel,
                              float* __restrict__ gatew,
                              int* __restrict__ counts) {
  int n = blockIdx.x;
  int lane = threadIdx.x;
  const float* xr = x + (size_t)n * CDIM;
  float acc[NEXP];
#pragma unroll
  for (int e = 0; e < NEXP; ++e) acc[e] = 0.f;
  for (int i = lane; i < CDIM; i += 64) {
    float xi = xr[i];
#pragma unroll
    for (int e = 0; e < NEXP; ++e) acc[e] += xi * rw[e * CDIM + i];
  }
#pragma unroll
  for (int off = 32; off > 0; off >>= 1) {
#pragma unroll
    for (int e = 0; e < NEXP; ++e) acc[e] += __shfl_xor(acc[e], off, 64);
  }
  if (lane == 0) {
    int i0 = 0; float v0 = acc[0];
#pragma unroll
    for (int e = 1; e < NEXP; ++e) if (acc[e] > v0) { v0 = acc[e]; i0 = e; }
    int i1 = (i0 == 0) ? 1 : 0; float v1 = acc[i1];
#pragma unroll
    for (int e = 0; e < NEXP; ++e) if (e != i0 && acc[e] > v1) { v1 = acc[e]; i1 = e; }
    sel[2 * n] = i0; sel[2 * n + 1] = i1;
    gatew[2 * n]     = 1.f / (1.f + expf(-v0));
    gatew[2 * n + 1] = 1.f / (1.f + expf(-v1));
    atomicAdd(&counts[i0], 1);
    atomicAdd(&counts[i1], 1);
  }
}

__global__ void scan_kernel(const int* __restrict__ counts,
                            int* __restrict__ offsets,
                            int* __restrict__ cursor,
                            int* __restrict__ tab128,
                            int* __restrict__ tab64,
                            int* __restrict__ ntiles) {
  if (threadIdx.x == 0) {
    int s = 0, a = 0, b = 0;
    for (int e = 0; e < NEXP; ++e) {
      offsets[e] = s; cursor[e] = s;
      int c = counts[e];
      for (int m0 = 0; m0 < c; m0 += 128) tab128[a++] = (e << 16) | m0;
      for (int m0 = 0; m0 < c; m0 += 64)  tab64[b++]  = (e << 16) | m0;
      s += c;
    }
    ntiles[0] = a; ntiles[1] = b;
  }
}

__global__ void scatter_kernel(const int* __restrict__ sel,
                               const float* __restrict__ gatew,
                               int* __restrict__ cursor,
                               int* __restrict__ entry_token,
                               float* __restrict__ entry_gate,
                               int* __restrict__ entry_pos) {
  int t = blockIdx.x * blockDim.x + threadIdx.x;
  if (t >= N_TOK * TOPK) return;
  int e = sel[t];
  int pos = atomicAdd(&cursor[e], 1);
  entry_token[pos] = t >> 1;
  entry_gate[pos] = gatew[t];
  entry_pos[t] = pos;
}

// ================= GU: gate+up GEMM (m97 structure: all-gload_lds) ==========
// Tile 128m x 64h dual-B, BK=64, 4 waves each 64m x 32h. B is bf16 n-major.
__global__ __launch_bounds__(256, 3)
void gu5(const bf16* __restrict__ xb,
         const bf16* __restrict__ guwb,    // [E][2048][1024] (rows: gate 0-1023, up 1024-2047)
         const bf16* __restrict__ sgwb,    // [2048][1024]
         const bf16* __restrict__ suwb,    // [2048][1024]
         bf16* __restrict__ h_exp,
         bf16* __restrict__ h_sh,
         const int* __restrict__ counts,
         const int* __restrict__ offsets,
         const int* __restrict__ entry_token,
         const int* __restrict__ tab128,
         const int* __restrict__ ntiles) {
  __shared__ __align__(16) bf16 sA[128 * 64];
  __shared__ __align__(16) bf16 sBg[64 * 64];
  __shared__ __align__(16) bf16 sBu[64 * 64];
  __shared__ int rowtok[128];

  const int bid = xcd_swz(blockIdx.x, GU_NWG);
  const int t = threadIdx.x;
  const bool is_exp = bid < GU_EXP_BLOCKS;
  const int wid = t >> 6, lane = t & 63;

  int n0, mguard;
  bf16* hbase; int hstride;
  const bf16 *Bg, *Bu;

  if (is_exp) {
    const int slot = bid >> 4;
    if (slot >= ntiles[0]) return;
    const int packed = tab128[slot];
    const int e = packed >> 16;
    const int m0 = packed & 0xffff;
    const int cnt = counts[e];
    const int base = offsets[e];
    n0 = (bid & 15) * 64;
    mguard = cnt - m0;
    if (t < 128) {
      int r = m0 + t;
      rowtok[t] = entry_token[base + ((r < cnt) ? r : (cnt - 1))];
    }
    const bf16* we = guwb + (size_t)e * (2 * HDIM) * CDIM;
    Bg = we + (size_t)n0 * CDIM;
    Bu = we + (size_t)(HDIM + n0) * CDIM;
    hbase = h_exp + (size_t)(base + m0) * HDIM + n0;
    hstride = HDIM;
  } else {
    const int sid = bid - GU_EXP_BLOCKS;
    const int m0 = (sid >> 5) * 128;
    n0 = (sid & 31) * 64;
    mguard = 128;
    if (t < 128) rowtok[t] = m0 + t;
    Bg = sgwb + (size_t)n0 * CDIM;
    Bu = suwb + (size_t)n0 * CDIM;
    hbase = h_sh + (size_t)m0 * SDIM + n0;
    hstride = SDIM;
  }
  __syncthreads();

  // staging addresses: linear LDS dest (t*16B), source-side chunk swizzle
  const int srow = t >> 3;                 // row within a 32-row group
  const int sc = (t & 7) ^ (srow & 7);     // (row&7) invariant under +32
  const bf16* asrc[4];
#pragma unroll
  for (int i = 0; i < 4; ++i)
    asrc[i] = xb + (size_t)rowtok[i * 32 + srow] * CDIM + sc * 8;
  const bf16* bg0 = Bg + (size_t)srow * CDIM + sc * 8;
  const bf16* bu0 = Bu + (size_t)srow * CDIM + sc * 8;
  const int adst = t * 8;                  // bf16 elements; block i adds 2048

  const int wr = (wid >> 1) * 64, wc = (wid & 1) * 32;
  const int lrow = lane & 15, grp = lane >> 4;

  f32x4 ag[4][2], au[4][2];
#pragma unroll
  for (int m = 0; m < 4; ++m)
#pragma unroll
    for (int n = 0; n < 2; ++n)
#pragma unroll
      for (int i = 0; i < 4; ++i) { ag[m][n][i] = 0.f; au[m][n][i] = 0.f; }

  for (int k0 = 0; k0 < CDIM; k0 += 64) {
#pragma unroll
    for (int i = 0; i < 4; ++i) gload16(asrc[i] + k0, &sA[adst + i * 2048]);
#pragma unroll
    for (int i = 0; i < 2; ++i) {
      gload16(bg0 + (size_t)i * 32 * CDIM + k0, &sBg[adst + i * 2048]);
      gload16(bu0 + (size_t)i * 32 * CDIM + k0, &sBu[adst + i * 2048]);
    }
    __syncthreads();
#pragma unroll
    for (int ks = 0; ks < 2; ++ks) {
      const int ch = ks * 4 + grp;
      bf16x8 av[4], bg[2], bu[2];
#pragma unroll
      for (int m = 0; m < 4; ++m) {
        const int r = wr + m * 16 + lrow;
        av[m] = *(const bf16x8*)&sA[r * 64 + ((ch ^ (r & 7)) << 3)];
      }
#pragma unroll
      for (int n = 0; n < 2; ++n) {
        const int r = wc + n * 16 + lrow;
        bg[n] = *(const bf16x8*)&sBg[r * 64 + ((ch ^ (r & 7)) << 3)];
        bu[n] = *(const bf16x8*)&sBu[r * 64 + ((ch ^ (r & 7)) << 3)];
      }
#pragma unroll
      for (int m = 0; m < 4; ++m)
#pragma unroll
        for (int n = 0; n < 2; ++n) {
          ag[m][n] = __builtin_amdgcn_mfma_f32_16x16x32_bf16(av[m], bg[n], ag[m][n], 0, 0, 0);
          au[m][n] = __builtin_amdgcn_mfma_f32_16x16x32_bf16(av[m], bu[n], au[m][n], 0, 0, 0);
        }
    }
    __syncthreads();
  }

  // SwiGLU epilogue (C/D: col=lane&15, row=grp*4+i)
#pragma unroll
  for (int m = 0; m < 4; ++m) {
#pragma unroll
    for (int i = 0; i < 4; ++i) {
      const int rl = wr + m * 16 + grp * 4 + i;
      if (rl >= mguard) continue;
      bf16* orow = hbase + (size_t)rl * hstride;
#pragma unroll
      for (int n = 0; n < 2; ++n) {
        const float g = ag[m][n][i];
        const float u = au[m][n][i];
        orow[wc + n * 16 + lrow] = (bf16)(g * u * __builtin_amdgcn_rcpf(1.f + __expf(-g)));
      }
    }
  }
}

// ================= DOWN GEMM (m97 structure) =================
// Tile 64m x 128n, BK=64, 4 waves each 32m x 64n. B is bf16 n-major.
__global__ __launch_bounds__(256, 4)
void dn5(const bf16* __restrict__ h_exp,
         const bf16* __restrict__ h_sh,
         const bf16* __restrict__ dwb,    // [E][1024][1024]
         const bf16* __restrict__ sdwb,   // [1024][2048]
         const float* __restrict__ entry_gate,
         bf16* __restrict__ out_e,
         float* __restrict__ out,
         const int* __restrict__ counts,
         const int* __restrict__ offsets,
         const int* __restrict__ tab64,
         const int* __restrict__ ntiles) {
  __shared__ __align__(16) bf16 sA[64 * 64];
  __shared__ __align__(16) bf16 sB[128 * 64];

  const int bid = xcd_swz(blockIdx.x, DN_NWG);
  const int t = threadIdx.x;
  const bool is_exp = bid < DN_EXP_BLOCKS;
  const int wid = t >> 6, lane = t & 63;

  int n0, mguard, K, rowbase;
  const bf16* Ab;
  const bf16* Bb;

  if (is_exp) {
    const int slot = bid >> 3;
    if (slot >= ntiles[1]) return;
    const int packed = tab64[slot];
    const int e = packed >> 16;
    const int m0 = packed & 0xffff;
    const int cnt = counts[e];
    n0 = (bid & 7) * 128;
    mguard = cnt - m0;
    K = HDIM;
    rowbase = offsets[e] + m0;
    Ab = h_exp;
    Bb = dwb + (size_t)e * CDIM * HDIM + (size_t)n0 * HDIM;
  } else {
    const int sid = bid - DN_EXP_BLOCKS;
    const int m0 = (sid >> 3) * 64;
    n0 = (sid & 7) * 128;
    mguard = 64;
    K = SDIM;
    rowbase = m0;
    Ab = h_sh;
    Bb = sdwb + (size_t)n0 * SDIM;
  }

  const int srow = t >> 3;
  const int sc = (t & 7) ^ (srow & 7);
  const bf16* asrc[2];
#pragma unroll
  for (int i = 0; i < 2; ++i) {
    int rg = rowbase + i * 32 + srow;
    if (is_exp && rg > N_TOK * TOPK - 1) rg = N_TOK * TOPK - 1;
    asrc[i] = Ab + (size_t)rg * K + sc * 8;
  }
  const bf16* b0 = Bb + (size_t)srow * K + sc * 8;
  const int adst = t * 8;

  const int wr = (wid >> 1) * 32, wc = (wid & 1) * 64;
  const int lrow = lane & 15, grp = lane >> 4;

  f32x4 acc[2][4];
#pragma unroll
  for (int m = 0; m < 2; ++m)
#pragma unroll
    for (int n = 0; n < 4; ++n)
#pragma unroll
      for (int i = 0; i < 4; ++i) acc[m][n][i] = 0.f;

  for (int k0 = 0; k0 < K; k0 += 64) {
#pragma unroll
    for (int i = 0; i < 2; ++i) gload16(asrc[i] + k0, &sA[adst + i * 2048]);
#pragma unroll
    for (int i = 0; i < 4; ++i)
      gload16(b0 + (size_t)i * 32 * K + k0, &sB[adst + i * 2048]);
    __syncthreads();
#pragma unroll
    for (int ks = 0; ks < 2; ++ks) {
      const int ch = ks * 4 + grp;
      bf16x8 av[2], bv[4];
#pragma unroll
      for (int m = 0; m < 2; ++m) {
        const int r = wr + m * 16 + lrow;
        av[m] = *(const bf16x8*)&sA[r * 64 + ((ch ^ (r & 7)) << 3)];
      }
#pragma unroll
      for (int n = 0; n < 4; ++n) {
        const int r = wc + n * 16 + lrow;
        bv[n] = *(const bf16x8*)&sB[r * 64 + ((ch ^ (r & 7)) << 3)];
      }
#pragma unroll
      for (int m = 0; m < 2; ++m)
#pragma unroll
        for (int n = 0; n < 4; ++n)
          acc[m][n] = __builtin_amdgcn_mfma_f32_16x16x32_bf16(av[m], bv[n], acc[m][n], 0, 0, 0);
    }
    __syncthreads();
  }

#pragma unroll
  for (int m = 0; m < 2; ++m) {
#pragma unroll
    for (int i = 0; i < 4; ++i) {
      const int rl = wr + m * 16 + grp * 4 + i;
      if (rl >= mguard) continue;
      if (is_exp) {
        const int row = rowbase + rl;
        const float scl = entry_gate[row];
        bf16* orow = out_e + (size_t)row * CDIM + n0;
#pragma unroll
        for (int n = 0; n < 4; ++n)
          orow[wc + n * 16 + lrow] = (bf16)(acc[m][n][i] * scl);
      } else {
        float* orow = out + (size_t)(rowbase + rl) * CDIM + n0;
#pragma unroll
        for (int n = 0; n < 4; ++n)
          orow[wc + n * 16 + lrow] = acc[m][n][i];
      }
    }
  }
}

// ---------------- combine ----------------
__global__ void combine_kernel(float* __restrict__ out,
                               const bf16* __restrict__ out_e,
                               const int* __restrict__ entry_pos) {
  int tid = blockIdx.x * blockDim.x + threadIdx.x;
  int n = tid >> 8;
  int c4 = tid & 255;
  int p0 = entry_pos[2 * n];
  int p1 = entry_pos[2 * n + 1];
  float4 v = ((const float4*)out)[tid];
  ushort4 a = *(const ushort4*)((const u16*)out_e + (size_t)p0 * CDIM + c4 * 4);
  ushort4 b = *(const ushort4*)((const u16*)out_e + (size_t)p1 * CDIM + c4 * 4);
  v.x += fromb(a.x) + fromb(b.x);
  v.y += fromb(a.y) + fromb(b.y);
  v.z += fromb(a.z) + fromb(b.z);
  v.w += fromb(a.w) + fromb(b.w);
  ((float4*)out)[tid] = v;
}

extern "C" void kernel_launch(void* const* d_in, const int* in_sizes, int n_in,
                              void* d_out, int out_size, void* d_ws, size_t ws_size,
                              hipStream_t stream) {
  const float* x   = (const float*)d_in[0];
  const float* rw  = (const float*)d_in[1];
  const float* guw = (const float*)d_in[2];
  const float* dw  = (const float*)d_in[3];
  const float* sgw = (const float*)d_in[4];
  const float* suw = (const float*)d_in[5];
  const float* sdw = (const float*)d_in[6];
  float* out = (float*)d_out;
  char* ws = (char*)d_ws;
  const size_t MB = 1048576;

  int*   sel         = (int*)(ws + 0);
  float* gatew       = (float*)(ws + 16384);
  int*   counts      = (int*)(ws + 32768);
  int*   offsets     = (int*)(ws + 32832);
  int*   cursor      = (int*)(ws + 32896);
  int*   ntiles      = (int*)(ws + 32960);
  int*   tab128      = (int*)(ws + 33024);   // 48 ints
  int*   tab64       = (int*)(ws + 33280);   // 80 ints
  int*   entry_token = (int*)(ws + 33664);
  float* entry_gate  = (float*)(ws + 50048);
  int*   entry_pos   = (int*)(ws + 66432);

  // big buffers (base 82816; peak need ~97 MB with aliasing)
  bf16* xb    = (bf16*)(ws + 82816);                 // 4 MB; later reused as sdw_b
  bf16* h_exp = (bf16*)(ws + 82816 + 4 * MB);        // 8 MB
  bf16* h_sh  = (bf16*)(ws + 82816 + 12 * MB);       // 8 MB
  bf16* sgw_b = (bf16*)(ws + 82816 + 20 * MB);       // 4 MB
  bf16* suw_b = (bf16*)(ws + 82816 + 24 * MB);       // 4 MB
  bf16* Wbig  = (bf16*)(ws + 82816 + 28 * MB);       // 64 MB: guw_b, then dw_b
  bf16* out_e = sgw_b;                               // 8 MB alias (dead after gu)
  bf16* sdw_b = xb;                                  // 4 MB alias (dead after gu)

  // phase 0a: canonicalize gu-side weights + x to bf16 (n-major)
  convert_plain<<<1024, 256, 0, stream>>>(x, xb);
  convert_t<<<dim3(32, 16, NEXP), 256, 0, stream>>>(guw, Wbig, CDIM, 2 * HDIM);
  convert_plain<<<1024, 256, 0, stream>>>(sgw, sgw_b);
  convert_plain<<<1024, 256, 0, stream>>>(suw, suw_b);

  // routing
  init_counts_kernel<<<1, 64, 0, stream>>>(counts);
  router_kernel<<<N_TOK, 64, 0, stream>>>(x, rw, sel, gatew, counts);
  scan_kernel<<<1, 64, 0, stream>>>(counts, offsets, cursor, tab128, tab64, ntiles);
  scatter_kernel<<<16, 256, 0, stream>>>(sel, gatew, cursor, entry_token, entry_gate, entry_pos);

  // gate+up + SwiGLU (expert + shared)
  gu5<<<GU_NWG, 256, 0, stream>>>(xb, Wbig, sgw_b, suw_b, h_exp, h_sh,
                                  counts, offsets, entry_token, tab128, ntiles);

  // phase 0b: canonicalize dn-side weights (into regions freed by gu)
  convert_t<<<dim3(16, 16, NEXP), 256, 0, stream>>>(dw, Wbig, HDIM, CDIM);
  convert_plain<<<1024, 256, 0, stream>>>(sdw, sdw_b);

  // down (expert + shared)
  dn5<<<DN_NWG, 256, 0, stream>>>(h_exp, h_sh, Wbig, sdw_b, entry_gate, out_e, out,
                                  counts, offsets, tab64, ntiles);

  // add gated expert contributions
  combine_kernel<<<(N_TOK * CDIM / 4) / 256, 256, 0, stream>>>(out, out_e, entry_pos);
}

// Round 9
// 237.653 us; speedup vs baseline: 1.4372x; 1.0123x over previous
//
#include <hip/hip_runtime.h>
#include <cstdint>

#define N_TOK 2048
#define CDIM  1024
#define NEXP  16
#define TOPK  2
#define HDIM  1024
#define SDIM  2048
#define ESLOT 48
#define ESLOT64 80
#define GU_EXP_BLOCKS (ESLOT * 16)              // 768
#define GU_SH_BLOCKS  (16 * 32)                 // 512
#define GU_NWG (GU_EXP_BLOCKS + GU_SH_BLOCKS)   // 1280
#define DN_EXP_BLOCKS (ESLOT64 * 8)             // 640
#define DN_SH_BLOCKS  (32 * 8)                  // 256
#define DN_NWG (DN_EXP_BLOCKS + DN_SH_BLOCKS)   // 896

typedef __bf16 bf16;
typedef __bf16 bf16x8 __attribute__((ext_vector_type(8)));
typedef float  f32x4  __attribute__((ext_vector_type(4)));
typedef unsigned int u32;
typedef unsigned short u16;

typedef __attribute__((address_space(3))) uint32_t lds_u32_t;
typedef __attribute__((address_space(1))) uint32_t glb_u32_t;

__device__ __forceinline__ void gload16(const void* g, void* l) {
  __builtin_amdgcn_global_load_lds((const glb_u32_t*)(uintptr_t)g,
                                   (lds_u32_t*)(uintptr_t)l, 16, 0, 0);
}
__device__ __forceinline__ float fromb(u16 s) {
  union { float f; u32 u; } z; z.u = ((u32)s) << 16; return z.f;
}
__device__ __forceinline__ int xcd_swz(int bid, int nwg) {
  return (bid & 7) * (nwg >> 3) + (bid >> 3);
}

// ---------------- weight canonicalization ----------------
__global__ void convert_plain(const float* __restrict__ s, bf16* __restrict__ d) {
  int i = (blockIdx.x * 256 + threadIdx.x) * 8;
  float4 f0 = *(const float4*)(s + i);
  float4 f1 = *(const float4*)(s + i + 4);
  bf16x8 v;
  v[0]=(bf16)f0.x; v[1]=(bf16)f0.y; v[2]=(bf16)f0.z; v[3]=(bf16)f0.w;
  v[4]=(bf16)f1.x; v[5]=(bf16)f1.y; v[6]=(bf16)f1.z; v[7]=(bf16)f1.w;
  *(bf16x8*)(d + i) = v;
}

// transpose-convert: src [E][K][N] fp32 -> dst [E][N][K] bf16 (64x64 tiles)
__global__ __launch_bounds__(256)
void convert_t(const float* __restrict__ src, bf16* __restrict__ dst, int K, int N) {
  __shared__ float ld[64 * 68];
  const int e = blockIdx.z;
  const int n0 = blockIdx.x * 64, k0 = blockIdx.y * 64;
  const float* s = src + (size_t)e * K * N;
  bf16* d = dst + (size_t)e * N * K;
  const int t = threadIdx.x;
  const int kk = t >> 4, c4 = (t & 15) * 4;
#pragma unroll
  for (int q = 0; q < 4; ++q) {
    float4 f = *(const float4*)(s + (size_t)(k0 + kk + q * 16) * N + n0 + c4);
    float* lp = &ld[(kk + q * 16) * 68 + c4];
    lp[0] = f.x; lp[1] = f.y; lp[2] = f.z; lp[3] = f.w;
  }
  __syncthreads();
  const int nn = t >> 2, kc = (t & 3) * 16;
  bf16x8 v0, v1;
#pragma unroll
  for (int j = 0; j < 8; ++j) {
    v0[j] = (bf16)ld[(kc + j) * 68 + nn];
    v1[j] = (bf16)ld[(kc + 8 + j) * 68 + nn];
  }
  bf16* dp = d + (size_t)(n0 + nn) * K + k0 + kc;
  *(bf16x8*)dp = v0;
  *(bf16x8*)(dp + 8) = v1;
}

// ---------------- router (fused x->bf16 conversion; no atomics) ----------------
__global__ void router_kernel(const float* __restrict__ x,
                              const float* __restrict__ rw,
                              bf16* __restrict__ xb,
                              int* __restrict__ sel,
                              float* __restrict__ gatew) {
  int n = blockIdx.x;
  int lane = threadIdx.x;   // 64 lanes; each owns 16 contiguous elems
  const float* xr = x + (size_t)n * CDIM;
  float xv[16];
#pragma unroll
  for (int q = 0; q < 4; ++q) {
    float4 f = *(const float4*)(xr + lane * 16 + q * 4);
    xv[q * 4 + 0] = f.x; xv[q * 4 + 1] = f.y; xv[q * 4 + 2] = f.z; xv[q * 4 + 3] = f.w;
  }
  // write bf16 copy of x
  bf16x8 v0, v1;
#pragma unroll
  for (int j = 0; j < 8; ++j) { v0[j] = (bf16)xv[j]; v1[j] = (bf16)xv[8 + j]; }
  bf16* xo = xb + (size_t)n * CDIM + lane * 16;
  *(bf16x8*)xo = v0;
  *(bf16x8*)(xo + 8) = v1;
  // router logits
  float acc[NEXP];
#pragma unroll
  for (int e = 0; e < NEXP; ++e) {
    float a = 0.f;
    const float* rwe = rw + e * CDIM + lane * 16;
#pragma unroll
    for (int j = 0; j < 16; ++j) a += xv[j] * rwe[j];
    acc[e] = a;
  }
#pragma unroll
  for (int off = 32; off > 0; off >>= 1) {
#pragma unroll
    for (int e = 0; e < NEXP; ++e) acc[e] += __shfl_xor(acc[e], off, 64);
  }
  if (lane == 0) {
    int i0 = 0; float v0_ = acc[0];
#pragma unroll
    for (int e = 1; e < NEXP; ++e) if (acc[e] > v0_) { v0_ = acc[e]; i0 = e; }
    int i1 = (i0 == 0) ? 1 : 0; float v1_ = acc[i1];
#pragma unroll
    for (int e = 0; e < NEXP; ++e) if (e != i0 && acc[e] > v1_) { v1_ = acc[e]; i1 = e; }
    sel[2 * n] = i0; sel[2 * n + 1] = i1;
    gatew[2 * n]     = 1.f / (1.f + expf(-v0_));
    gatew[2 * n + 1] = 1.f / (1.f + expf(-v1_));
  }
}

// scan: histogram of sel -> counts/offsets/cursor + tile tables
__global__ void scan_kernel(const int* __restrict__ sel,
                            int* __restrict__ counts,
                            int* __restrict__ offsets,
                            int* __restrict__ cursor,
                            int* __restrict__ tab128,
                            int* __restrict__ tab64,
                            int* __restrict__ ntiles) {
  __shared__ int hist[NEXP];
  const int t = threadIdx.x;
  if (t < NEXP) hist[t] = 0;
  __syncthreads();
  for (int i = t; i < N_TOK * TOPK; i += 256) atomicAdd(&hist[sel[i]], 1);
  __syncthreads();
  if (t == 0) {
    int s = 0, a = 0, b = 0;
    for (int e = 0; e < NEXP; ++e) {
      int c = hist[e];
      counts[e] = c; offsets[e] = s; cursor[e] = s;
      for (int m0 = 0; m0 < c; m0 += 128) tab128[a++] = (e << 16) | m0;
      for (int m0 = 0; m0 < c; m0 += 64)  tab64[b++]  = (e << 16) | m0;
      s += c;
    }
    ntiles[0] = a; ntiles[1] = b;
  }
}

__global__ void scatter_kernel(const int* __restrict__ sel,
                               const float* __restrict__ gatew,
                               int* __restrict__ cursor,
                               int* __restrict__ entry_token,
                               float* __restrict__ entry_gate,
                               int* __restrict__ entry_pos) {
  int t = blockIdx.x * blockDim.x + threadIdx.x;
  if (t >= N_TOK * TOPK) return;
  int e = sel[t];
  int pos = atomicAdd(&cursor[e], 1);
  entry_token[pos] = t >> 1;
  entry_gate[pos] = gatew[t];
  entry_pos[t] = pos;
}

// ================= GU: gate+up GEMM (m97 structure: all-gload_lds) ==========
// Tile 128m x 64h dual-B, BK=64, 4 waves each 64m x 32h. B is bf16 n-major.
__global__ __launch_bounds__(256, 4)
void gu5(const bf16* __restrict__ xb,
         const bf16* __restrict__ guwb,    // [E][2048][1024]
         const bf16* __restrict__ sgwb,
         const bf16* __restrict__ suwb,
         bf16* __restrict__ h_exp,
         bf16* __restrict__ h_sh,
         const int* __restrict__ counts,
         const int* __restrict__ offsets,
         const int* __restrict__ entry_token,
         const int* __restrict__ tab128,
         const int* __restrict__ ntiles) {
  __shared__ __align__(16) bf16 sA[128 * 64];
  __shared__ __align__(16) bf16 sBg[64 * 64];
  __shared__ __align__(16) bf16 sBu[64 * 64];
  __shared__ int rowtok[128];

  const int bid = xcd_swz(blockIdx.x, GU_NWG);
  const int t = threadIdx.x;
  const bool is_exp = bid < GU_EXP_BLOCKS;
  const int wid = t >> 6, lane = t & 63;

  int n0, mguard;
  bf16* hbase; int hstride;
  const bf16 *Bg, *Bu;

  if (is_exp) {
    const int slot = bid >> 4;
    if (slot >= ntiles[0]) return;
    const int packed = tab128[slot];
    const int e = packed >> 16;
    const int m0 = packed & 0xffff;
    const int cnt = counts[e];
    const int base = offsets[e];
    n0 = (bid & 15) * 64;
    mguard = cnt - m0;
    if (t < 128) {
      int r = m0 + t;
      rowtok[t] = entry_token[base + ((r < cnt) ? r : (cnt - 1))];
    }
    const bf16* we = guwb + (size_t)e * (2 * HDIM) * CDIM;
    Bg = we + (size_t)n0 * CDIM;
    Bu = we + (size_t)(HDIM + n0) * CDIM;
    hbase = h_exp + (size_t)(base + m0) * HDIM + n0;
    hstride = HDIM;
  } else {
    const int sid = bid - GU_EXP_BLOCKS;
    const int m0 = (sid >> 5) * 128;
    n0 = (sid & 31) * 64;
    mguard = 128;
    if (t < 128) rowtok[t] = m0 + t;
    Bg = sgwb + (size_t)n0 * CDIM;
    Bu = suwb + (size_t)n0 * CDIM;
    hbase = h_sh + (size_t)m0 * SDIM + n0;
    hstride = SDIM;
  }
  __syncthreads();

  const int srow = t >> 3;
  const int sc = (t & 7) ^ (srow & 7);
  const bf16* asrc[4];
#pragma unroll
  for (int i = 0; i < 4; ++i)
    asrc[i] = xb + (size_t)rowtok[i * 32 + srow] * CDIM + sc * 8;
  const bf16* bg0 = Bg + (size_t)srow * CDIM + sc * 8;
  const bf16* bu0 = Bu + (size_t)srow * CDIM + sc * 8;
  const int adst = t * 8;

  const int wr = (wid >> 1) * 64, wc = (wid & 1) * 32;
  const int lrow = lane & 15, grp = lane >> 4;

  f32x4 ag[4][2], au[4][2];
#pragma unroll
  for (int m = 0; m < 4; ++m)
#pragma unroll
    for (int n = 0; n < 2; ++n)
#pragma unroll
      for (int i = 0; i < 4; ++i) { ag[m][n][i] = 0.f; au[m][n][i] = 0.f; }

  for (int k0 = 0; k0 < CDIM; k0 += 64) {
#pragma unroll
    for (int i = 0; i < 4; ++i) gload16(asrc[i] + k0, &sA[adst + i * 2048]);
#pragma unroll
    for (int i = 0; i < 2; ++i) {
      gload16(bg0 + (size_t)i * 32 * CDIM + k0, &sBg[adst + i * 2048]);
      gload16(bu0 + (size_t)i * 32 * CDIM + k0, &sBu[adst + i * 2048]);
    }
    __syncthreads();
#pragma unroll
    for (int ks = 0; ks < 2; ++ks) {
      const int ch = ks * 4 + grp;
      bf16x8 av[4], bg[2], bu[2];
#pragma unroll
      for (int m = 0; m < 4; ++m) {
        const int r = wr + m * 16 + lrow;
        av[m] = *(const bf16x8*)&sA[r * 64 + ((ch ^ (r & 7)) << 3)];
      }
#pragma unroll
      for (int n = 0; n < 2; ++n) {
        const int r = wc + n * 16 + lrow;
        bg[n] = *(const bf16x8*)&sBg[r * 64 + ((ch ^ (r & 7)) << 3)];
        bu[n] = *(const bf16x8*)&sBu[r * 64 + ((ch ^ (r & 7)) << 3)];
      }
#pragma unroll
      for (int m = 0; m < 4; ++m)
#pragma unroll
        for (int n = 0; n < 2; ++n) {
          ag[m][n] = __builtin_amdgcn_mfma_f32_16x16x32_bf16(av[m], bg[n], ag[m][n], 0, 0, 0);
          au[m][n] = __builtin_amdgcn_mfma_f32_16x16x32_bf16(av[m], bu[n], au[m][n], 0, 0, 0);
        }
    }
    __syncthreads();
  }

#pragma unroll
  for (int m = 0; m < 4; ++m) {
#pragma unroll
    for (int i = 0; i < 4; ++i) {
      const int rl = wr + m * 16 + grp * 4 + i;
      if (rl >= mguard) continue;
      bf16* orow = hbase + (size_t)rl * hstride;
#pragma unroll
      for (int n = 0; n < 2; ++n) {
        const float g = ag[m][n][i];
        const float u = au[m][n][i];
        orow[wc + n * 16 + lrow] = (bf16)(g * u * __builtin_amdgcn_rcpf(1.f + __expf(-g)));
      }
    }
  }
}

// ================= DOWN GEMM (m97 structure) =================
__global__ __launch_bounds__(256, 4)
void dn5(const bf16* __restrict__ h_exp,
         const bf16* __restrict__ h_sh,
         const bf16* __restrict__ dwb,    // [E][1024][1024]
         const bf16* __restrict__ sdwb,   // [1024][2048]
         const float* __restrict__ entry_gate,
         bf16* __restrict__ out_e,
         float* __restrict__ out,
         const int* __restrict__ counts,
         const int* __restrict__ offsets,
         const int* __restrict__ tab64,
         const int* __restrict__ ntiles) {
  __shared__ __align__(16) bf16 sA[64 * 64];
  __shared__ __align__(16) bf16 sB[128 * 64];

  const int bid = xcd_swz(blockIdx.x, DN_NWG);
  const int t = threadIdx.x;
  const bool is_exp = bid < DN_EXP_BLOCKS;
  const int wid = t >> 6, lane = t & 63;

  int n0, mguard, K, rowbase;
  const bf16* Ab;
  const bf16* Bb;

  if (is_exp) {
    const int slot = bid >> 3;
    if (slot >= ntiles[1]) return;
    const int packed = tab64[slot];
    const int e = packed >> 16;
    const int m0 = packed & 0xffff;
    const int cnt = counts[e];
    n0 = (bid & 7) * 128;
    mguard = cnt - m0;
    K = HDIM;
    rowbase = offsets[e] + m0;
    Ab = h_exp;
    Bb = dwb + (size_t)e * CDIM * HDIM + (size_t)n0 * HDIM;
  } else {
    const int sid = bid - DN_EXP_BLOCKS;
    const int m0 = (sid >> 3) * 64;
    n0 = (sid & 7) * 128;
    mguard = 64;
    K = SDIM;
    rowbase = m0;
    Ab = h_sh;
    Bb = sdwb + (size_t)n0 * SDIM;
  }

  const int srow = t >> 3;
  const int sc = (t & 7) ^ (srow & 7);
  const bf16* asrc[2];
#pragma unroll
  for (int i = 0; i < 2; ++i) {
    int rg = rowbase + i * 32 + srow;
    if (is_exp && rg > N_TOK * TOPK - 1) rg = N_TOK * TOPK - 1;
    asrc[i] = Ab + (size_t)rg * K + sc * 8;
  }
  const bf16* b0 = Bb + (size_t)srow * K + sc * 8;
  const int adst = t * 8;

  const int wr = (wid >> 1) * 32, wc = (wid & 1) * 64;
  const int lrow = lane & 15, grp = lane >> 4;

  f32x4 acc[2][4];
#pragma unroll
  for (int m = 0; m < 2; ++m)
#pragma unroll
    for (int n = 0; n < 4; ++n)
#pragma unroll
      for (int i = 0; i < 4; ++i) acc[m][n][i] = 0.f;

  for (int k0 = 0; k0 < K; k0 += 64) {
#pragma unroll
    for (int i = 0; i < 2; ++i) gload16(asrc[i] + k0, &sA[adst + i * 2048]);
#pragma unroll
    for (int i = 0; i < 4; ++i)
      gload16(b0 + (size_t)i * 32 * K + k0, &sB[adst + i * 2048]);
    __syncthreads();
#pragma unroll
    for (int ks = 0; ks < 2; ++ks) {
      const int ch = ks * 4 + grp;
      bf16x8 av[2], bv[4];
#pragma unroll
      for (int m = 0; m < 2; ++m) {
        const int r = wr + m * 16 + lrow;
        av[m] = *(const bf16x8*)&sA[r * 64 + ((ch ^ (r & 7)) << 3)];
      }
#pragma unroll
      for (int n = 0; n < 4; ++n) {
        const int r = wc + n * 16 + lrow;
        bv[n] = *(const bf16x8*)&sB[r * 64 + ((ch ^ (r & 7)) << 3)];
      }
#pragma unroll
      for (int m = 0; m < 2; ++m)
#pragma unroll
        for (int n = 0; n < 4; ++n)
          acc[m][n] = __builtin_amdgcn_mfma_f32_16x16x32_bf16(av[m], bv[n], acc[m][n], 0, 0, 0);
    }
    __syncthreads();
  }

#pragma unroll
  for (int m = 0; m < 2; ++m) {
#pragma unroll
    for (int i = 0; i < 4; ++i) {
      const int rl = wr + m * 16 + grp * 4 + i;
      if (rl >= mguard) continue;
      if (is_exp) {
        const int row = rowbase + rl;
        const float scl = entry_gate[row];
        bf16* orow = out_e + (size_t)row * CDIM + n0;
#pragma unroll
        for (int n = 0; n < 4; ++n)
          orow[wc + n * 16 + lrow] = (bf16)(acc[m][n][i] * scl);
      } else {
        float* orow = out + (size_t)(rowbase + rl) * CDIM + n0;
#pragma unroll
        for (int n = 0; n < 4; ++n)
          orow[wc + n * 16 + lrow] = acc[m][n][i];
      }
    }
  }
}

// ---------------- combine ----------------
__global__ void combine_kernel(float* __restrict__ out,
                               const bf16* __restrict__ out_e,
                               const int* __restrict__ entry_pos) {
  int tid = blockIdx.x * blockDim.x + threadIdx.x;
  int n = tid >> 8;
  int c4 = tid & 255;
  int p0 = entry_pos[2 * n];
  int p1 = entry_pos[2 * n + 1];
  float4 v = ((const float4*)out)[tid];
  ushort4 a = *(const ushort4*)((const u16*)out_e + (size_t)p0 * CDIM + c4 * 4);
  ushort4 b = *(const ushort4*)((const u16*)out_e + (size_t)p1 * CDIM + c4 * 4);
  v.x += fromb(a.x) + fromb(b.x);
  v.y += fromb(a.y) + fromb(b.y);
  v.z += fromb(a.z) + fromb(b.z);
  v.w += fromb(a.w) + fromb(b.w);
  ((float4*)out)[tid] = v;
}

extern "C" void kernel_launch(void* const* d_in, const int* in_sizes, int n_in,
                              void* d_out, int out_size, void* d_ws, size_t ws_size,
                              hipStream_t stream) {
  const float* x   = (const float*)d_in[0];
  const float* rw  = (const float*)d_in[1];
  const float* guw = (const float*)d_in[2];
  const float* dw  = (const float*)d_in[3];
  const float* sgw = (const float*)d_in[4];
  const float* suw = (const float*)d_in[5];
  const float* sdw = (const float*)d_in[6];
  float* out = (float*)d_out;
  char* ws = (char*)d_ws;
  const size_t MB = 1048576;

  int*   sel         = (int*)(ws + 0);
  float* gatew       = (float*)(ws + 16384);
  int*   counts      = (int*)(ws + 32768);
  int*   offsets     = (int*)(ws + 32832);
  int*   cursor      = (int*)(ws + 32896);
  int*   ntiles      = (int*)(ws + 32960);
  int*   tab128      = (int*)(ws + 33024);   // 48 ints
  int*   tab64       = (int*)(ws + 33280);   // 80 ints
  int*   entry_token = (int*)(ws + 33664);
  float* entry_gate  = (float*)(ws + 50048);
  int*   entry_pos   = (int*)(ws + 66432);

  bf16* xb    = (bf16*)(ws + 82816);                 // 4 MB; later reused as sdw_b
  bf16* h_exp = (bf16*)(ws + 82816 + 4 * MB);        // 8 MB
  bf16* h_sh  = (bf16*)(ws + 82816 + 12 * MB);       // 8 MB
  bf16* sgw_b = (bf16*)(ws + 82816 + 20 * MB);       // 4 MB
  bf16* suw_b = (bf16*)(ws + 82816 + 24 * MB);       // 4 MB
  bf16* Wbig  = (bf16*)(ws + 82816 + 28 * MB);       // 64 MB: guw_b, then dw_b
  bf16* out_e = sgw_b;                               // 8 MB alias (dead after gu)
  bf16* sdw_b = xb;                                  // 4 MB alias (dead after gu)

  // routing + fused x conversion
  router_kernel<<<N_TOK, 64, 0, stream>>>(x, rw, xb, sel, gatew);
  scan_kernel<<<1, 256, 0, stream>>>(sel, counts, offsets, cursor, tab128, tab64, ntiles);
  scatter_kernel<<<16, 256, 0, stream>>>(sel, gatew, cursor, entry_token, entry_gate, entry_pos);

  // canonicalize gu-side weights
  convert_t<<<dim3(32, 16, NEXP), 256, 0, stream>>>(guw, Wbig, CDIM, 2 * HDIM);
  convert_plain<<<1024, 256, 0, stream>>>(sgw, sgw_b);
  convert_plain<<<1024, 256, 0, stream>>>(suw, suw_b);

  // gate+up + SwiGLU (expert + shared)
  gu5<<<GU_NWG, 256, 0, stream>>>(xb, Wbig, sgw_b, suw_b, h_exp, h_sh,
                                  counts, offsets, entry_token, tab128, ntiles);

  // canonicalize dn-side weights (into regions freed by gu)
  convert_t<<<dim3(16, 16, NEXP), 256, 0, stream>>>(dw, Wbig, HDIM, CDIM);
  convert_plain<<<1024, 256, 0, stream>>>(sdw, sdw_b);

  // down (expert + shared)
  dn5<<<DN_NWG, 256, 0, stream>>>(h_exp, h_sh, Wbig, sdw_b, entry_gate, out_e, out,
                                  counts, offsets, tab64, ntiles);

  // add gated expert contributions
  combine_kernel<<<(N_TOK * CDIM / 4) / 256, 256, 0, stream>>>(out, out_e, entry_pos);
}

// Round 10
// 201.628 us; speedup vs baseline: 1.6939x; 1.1787x over previous
//
#include <hip/hip_runtime.h>
#include <cstdint>

#define N_TOK 2048
#define CDIM  1024
#define NEXP  16
#define TOPK  2
#define HDIM  1024
#define SDIM  2048
#define ESLOT 48
#define ESLOT64 80
#define GU_EXP_BLOCKS (ESLOT * 16)              // 768
#define GU_SH_BLOCKS  (16 * 32)                 // 512
#define GU_NWG (GU_EXP_BLOCKS + GU_SH_BLOCKS)   // 1280
#define DN_EXP_BLOCKS (ESLOT64 * 8)             // 640
#define DN_SH_BLOCKS  (32 * 8)                  // 256
#define DN_NWG (DN_EXP_BLOCKS + DN_SH_BLOCKS)   // 896

typedef __bf16 bf16;
typedef __bf16 bf16x8 __attribute__((ext_vector_type(8)));
typedef float  f32x4  __attribute__((ext_vector_type(4)));
typedef unsigned int u32;
typedef unsigned short u16;

typedef __attribute__((address_space(3))) uint32_t lds_u32_t;
typedef __attribute__((address_space(1))) uint32_t glb_u32_t;

__device__ __forceinline__ void gload16(const void* g, void* l) {
  __builtin_amdgcn_global_load_lds((const glb_u32_t*)(uintptr_t)g,
                                   (lds_u32_t*)(uintptr_t)l, 16, 0, 0);
}
__device__ __forceinline__ float fromb(u16 s) {
  union { float f; u32 u; } z; z.u = ((u32)s) << 16; return z.f;
}
__device__ __forceinline__ int xcd_swz(int bid, int nwg) {
  return (bid & 7) * (nwg >> 3) + (bid >> 3);
}

// ---------------- weight canonicalization ----------------
__global__ void convert_plain(const float* __restrict__ s, bf16* __restrict__ d) {
  int i = (blockIdx.x * 256 + threadIdx.x) * 8;
  float4 f0 = *(const float4*)(s + i);
  float4 f1 = *(const float4*)(s + i + 4);
  bf16x8 v;
  v[0]=(bf16)f0.x; v[1]=(bf16)f0.y; v[2]=(bf16)f0.z; v[3]=(bf16)f0.w;
  v[4]=(bf16)f1.x; v[5]=(bf16)f1.y; v[6]=(bf16)f1.z; v[7]=(bf16)f1.w;
  *(bf16x8*)(d + i) = v;
}

// transpose-convert: src [E][K][N] fp32 -> dst [E][N][K] bf16 (64x64 tiles)
__global__ __launch_bounds__(256)
void convert_t(const float* __restrict__ src, bf16* __restrict__ dst, int K, int N) {
  __shared__ float ld[64 * 68];
  const int e = blockIdx.z;
  const int n0 = blockIdx.x * 64, k0 = blockIdx.y * 64;
  const float* s = src + (size_t)e * K * N;
  bf16* d = dst + (size_t)e * N * K;
  const int t = threadIdx.x;
  const int kk = t >> 4, c4 = (t & 15) * 4;
#pragma unroll
  for (int q = 0; q < 4; ++q) {
    float4 f = *(const float4*)(s + (size_t)(k0 + kk + q * 16) * N + n0 + c4);
    float* lp = &ld[(kk + q * 16) * 68 + c4];
    lp[0] = f.x; lp[1] = f.y; lp[2] = f.z; lp[3] = f.w;
  }
  __syncthreads();
  const int nn = t >> 2, kc = (t & 3) * 16;
  bf16x8 v0, v1;
#pragma unroll
  for (int j = 0; j < 8; ++j) {
    v0[j] = (bf16)ld[(kc + j) * 68 + nn];
    v1[j] = (bf16)ld[(kc + 8 + j) * 68 + nn];
  }
  bf16* dp = d + (size_t)(n0 + nn) * K + k0 + kc;
  *(bf16x8*)dp = v0;
  *(bf16x8*)(dp + 8) = v1;
}

// ---------------- router (fused x->bf16 conversion; no atomics) ----------------
__global__ void router_kernel(const float* __restrict__ x,
                              const float* __restrict__ rw,
                              bf16* __restrict__ xb,
                              int* __restrict__ sel,
                              float* __restrict__ gatew) {
  int n = blockIdx.x;
  int lane = threadIdx.x;
  const float* xr = x + (size_t)n * CDIM;
  float xv[16];
#pragma unroll
  for (int q = 0; q < 4; ++q) {
    float4 f = *(const float4*)(xr + lane * 16 + q * 4);
    xv[q * 4 + 0] = f.x; xv[q * 4 + 1] = f.y; xv[q * 4 + 2] = f.z; xv[q * 4 + 3] = f.w;
  }
  bf16x8 v0, v1;
#pragma unroll
  for (int j = 0; j < 8; ++j) { v0[j] = (bf16)xv[j]; v1[j] = (bf16)xv[8 + j]; }
  bf16* xo = xb + (size_t)n * CDIM + lane * 16;
  *(bf16x8*)xo = v0;
  *(bf16x8*)(xo + 8) = v1;
  float acc[NEXP];
#pragma unroll
  for (int e = 0; e < NEXP; ++e) {
    float a = 0.f;
    const float* rwe = rw + e * CDIM + lane * 16;
#pragma unroll
    for (int j = 0; j < 16; ++j) a += xv[j] * rwe[j];
    acc[e] = a;
  }
#pragma unroll
  for (int off = 32; off > 0; off >>= 1) {
#pragma unroll
    for (int e = 0; e < NEXP; ++e) acc[e] += __shfl_xor(acc[e], off, 64);
  }
  if (lane == 0) {
    int i0 = 0; float v0_ = acc[0];
#pragma unroll
    for (int e = 1; e < NEXP; ++e) if (acc[e] > v0_) { v0_ = acc[e]; i0 = e; }
    int i1 = (i0 == 0) ? 1 : 0; float v1_ = acc[i1];
#pragma unroll
    for (int e = 0; e < NEXP; ++e) if (e != i0 && acc[e] > v1_) { v1_ = acc[e]; i1 = e; }
    sel[2 * n] = i0; sel[2 * n + 1] = i1;
    gatew[2 * n]     = 1.f / (1.f + expf(-v0_));
    gatew[2 * n + 1] = 1.f / (1.f + expf(-v1_));
  }
}

__global__ void scan_kernel(const int* __restrict__ sel,
                            int* __restrict__ counts,
                            int* __restrict__ offsets,
                            int* __restrict__ cursor,
                            int* __restrict__ tab128,
                            int* __restrict__ tab64,
                            int* __restrict__ ntiles) {
  __shared__ int hist[NEXP];
  const int t = threadIdx.x;
  if (t < NEXP) hist[t] = 0;
  __syncthreads();
  for (int i = t; i < N_TOK * TOPK; i += 256) atomicAdd(&hist[sel[i]], 1);
  __syncthreads();
  if (t == 0) {
    int s = 0, a = 0, b = 0;
    for (int e = 0; e < NEXP; ++e) {
      int c = hist[e];
      counts[e] = c; offsets[e] = s; cursor[e] = s;
      for (int m0 = 0; m0 < c; m0 += 128) tab128[a++] = (e << 16) | m0;
      for (int m0 = 0; m0 < c; m0 += 64)  tab64[b++]  = (e << 16) | m0;
      s += c;
    }
    ntiles[0] = a; ntiles[1] = b;
  }
}

__global__ void scatter_kernel(const int* __restrict__ sel,
                               const float* __restrict__ gatew,
                               int* __restrict__ cursor,
                               int* __restrict__ entry_token,
                               float* __restrict__ entry_gate,
                               int* __restrict__ entry_pos) {
  int t = blockIdx.x * blockDim.x + threadIdx.x;
  if (t >= N_TOK * TOPK) return;
  int e = sel[t];
  int pos = atomicAdd(&cursor[e], 1);
  entry_token[pos] = t >> 1;
  entry_gate[pos] = gatew[t];
  entry_pos[t] = pos;
}

// ================= GU: gate+up GEMM, double-buffered gload_lds pipeline ========
// Tile 128m x 64h dual-B, BK=64, 4 waves each 64m x 32h. One barrier per K-step.
__global__ __launch_bounds__(256, 2)
void gu6(const bf16* __restrict__ xb,
         const bf16* __restrict__ guwb,    // [E][2048][1024]
         const bf16* __restrict__ sgwb,
         const bf16* __restrict__ suwb,
         bf16* __restrict__ h_exp,
         bf16* __restrict__ h_sh,
         const int* __restrict__ counts,
         const int* __restrict__ offsets,
         const int* __restrict__ entry_token,
         const int* __restrict__ tab128,
         const int* __restrict__ ntiles) {
  __shared__ __align__(16) bf16 sA[2 * 8192];    // 2 x 128x64
  __shared__ __align__(16) bf16 sBg[2 * 4096];   // 2 x 64x64
  __shared__ __align__(16) bf16 sBu[2 * 4096];
  __shared__ int rowtok[128];

  const int bid = xcd_swz(blockIdx.x, GU_NWG);
  const int t = threadIdx.x;
  const bool is_exp = bid < GU_EXP_BLOCKS;
  const int wid = t >> 6, lane = t & 63;

  int n0, mguard;
  bf16* hbase; int hstride;
  const bf16 *Bg, *Bu;

  if (is_exp) {
    const int slot = bid >> 4;
    if (slot >= ntiles[0]) return;
    const int packed = tab128[slot];
    const int e = packed >> 16;
    const int m0 = packed & 0xffff;
    const int cnt = counts[e];
    const int base = offsets[e];
    n0 = (bid & 15) * 64;
    mguard = cnt - m0;
    if (t < 128) {
      int r = m0 + t;
      rowtok[t] = entry_token[base + ((r < cnt) ? r : (cnt - 1))];
    }
    const bf16* we = guwb + (size_t)e * (2 * HDIM) * CDIM;
    Bg = we + (size_t)n0 * CDIM;
    Bu = we + (size_t)(HDIM + n0) * CDIM;
    hbase = h_exp + (size_t)(base + m0) * HDIM + n0;
    hstride = HDIM;
  } else {
    const int sid = bid - GU_EXP_BLOCKS;
    const int m0 = (sid >> 5) * 128;
    n0 = (sid & 31) * 64;
    mguard = 128;
    if (t < 128) rowtok[t] = m0 + t;
    Bg = sgwb + (size_t)n0 * CDIM;
    Bu = suwb + (size_t)n0 * CDIM;
    hbase = h_sh + (size_t)m0 * SDIM + n0;
    hstride = SDIM;
  }
  __syncthreads();

  const int srow = t >> 3;
  const int sc = (t & 7) ^ (srow & 7);
  const bf16* asrc[4];
#pragma unroll
  for (int i = 0; i < 4; ++i)
    asrc[i] = xb + (size_t)rowtok[i * 32 + srow] * CDIM + sc * 8;
  const bf16* bg0 = Bg + (size_t)srow * CDIM + sc * 8;
  const bf16* bu0 = Bu + (size_t)srow * CDIM + sc * 8;
  const int adst = t * 8;

#define ISSUE(k_, pb_)                                                        \
  do {                                                                        \
    _Pragma("unroll")                                                         \
    for (int i = 0; i < 4; ++i)                                               \
      gload16(asrc[i] + (k_), &sA[(pb_) * 8192 + adst + i * 2048]);           \
    _Pragma("unroll")                                                         \
    for (int i = 0; i < 2; ++i) {                                             \
      gload16(bg0 + (size_t)i * 32 * CDIM + (k_),                             \
              &sBg[(pb_) * 4096 + adst + i * 2048]);                          \
      gload16(bu0 + (size_t)i * 32 * CDIM + (k_),                             \
              &sBu[(pb_) * 4096 + adst + i * 2048]);                          \
    }                                                                         \
  } while (0)

  const int wr = (wid >> 1) * 64, wc = (wid & 1) * 32;
  const int lrow = lane & 15, grp = lane >> 4;

  f32x4 ag[4][2], au[4][2];
#pragma unroll
  for (int m = 0; m < 4; ++m)
#pragma unroll
    for (int n = 0; n < 2; ++n)
#pragma unroll
      for (int i = 0; i < 4; ++i) { ag[m][n][i] = 0.f; au[m][n][i] = 0.f; }

  ISSUE(0, 0);
  __syncthreads();

  int p = 0;
  for (int k0 = 0; k0 < CDIM; k0 += 64) {
    const int kn = k0 + 64;
    if (kn < CDIM) ISSUE(kn, p ^ 1);    // in flight across the compute phase
#pragma unroll
    for (int ks = 0; ks < 2; ++ks) {
      const int ch = ks * 4 + grp;
      bf16x8 av[4], bg[2], bu[2];
#pragma unroll
      for (int m = 0; m < 4; ++m) {
        const int r = wr + m * 16 + lrow;
        av[m] = *(const bf16x8*)&sA[p * 8192 + r * 64 + ((ch ^ (r & 7)) << 3)];
      }
#pragma unroll
      for (int n = 0; n < 2; ++n) {
        const int r = wc + n * 16 + lrow;
        bg[n] = *(const bf16x8*)&sBg[p * 4096 + r * 64 + ((ch ^ (r & 7)) << 3)];
        bu[n] = *(const bf16x8*)&sBu[p * 4096 + r * 64 + ((ch ^ (r & 7)) << 3)];
      }
#pragma unroll
      for (int m = 0; m < 4; ++m)
#pragma unroll
        for (int n = 0; n < 2; ++n) {
          ag[m][n] = __builtin_amdgcn_mfma_f32_16x16x32_bf16(av[m], bg[n], ag[m][n], 0, 0, 0);
          au[m][n] = __builtin_amdgcn_mfma_f32_16x16x32_bf16(av[m], bu[n], au[m][n], 0, 0, 0);
        }
    }
    __syncthreads();   // drains next-step loads; all waves done reading buf p
    p ^= 1;
  }
#undef ISSUE

  // SwiGLU epilogue (C/D: col=lane&15, row=grp*4+i)
#pragma unroll
  for (int m = 0; m < 4; ++m) {
#pragma unroll
    for (int i = 0; i < 4; ++i) {
      const int rl = wr + m * 16 + grp * 4 + i;
      if (rl >= mguard) continue;
      bf16* orow = hbase + (size_t)rl * hstride;
#pragma unroll
      for (int n = 0; n < 2; ++n) {
        const float g = ag[m][n][i];
        const float u = au[m][n][i];
        orow[wc + n * 16 + lrow] = (bf16)(g * u * __builtin_amdgcn_rcpf(1.f + __expf(-g)));
      }
    }
  }
}

// ================= DOWN GEMM, double-buffered gload_lds pipeline =============
// Tile 64m x 128n, BK=64, 4 waves each 32m x 64n. One barrier per K-step.
__global__ __launch_bounds__(256, 3)
void dn6(const bf16* __restrict__ h_exp,
         const bf16* __restrict__ h_sh,
         const bf16* __restrict__ dwb,    // [E][1024][1024]
         const bf16* __restrict__ sdwb,   // [1024][2048]
         const float* __restrict__ entry_gate,
         bf16* __restrict__ out_e,
         float* __restrict__ out,
         const int* __restrict__ counts,
         const int* __restrict__ offsets,
         const int* __restrict__ tab64,
         const int* __restrict__ ntiles) {
  __shared__ __align__(16) bf16 sA[2 * 4096];    // 2 x 64x64
  __shared__ __align__(16) bf16 sB[2 * 8192];    // 2 x 128x64

  const int bid = xcd_swz(blockIdx.x, DN_NWG);
  const int t = threadIdx.x;
  const bool is_exp = bid < DN_EXP_BLOCKS;
  const int wid = t >> 6, lane = t & 63;

  int n0, mguard, K, rowbase;
  const bf16* Ab;
  const bf16* Bb;

  if (is_exp) {
    const int slot = bid >> 3;
    if (slot >= ntiles[1]) return;
    const int packed = tab64[slot];
    const int e = packed >> 16;
    const int m0 = packed & 0xffff;
    const int cnt = counts[e];
    n0 = (bid & 7) * 128;
    mguard = cnt - m0;
    K = HDIM;
    rowbase = offsets[e] + m0;
    Ab = h_exp;
    Bb = dwb + (size_t)e * CDIM * HDIM + (size_t)n0 * HDIM;
  } else {
    const int sid = bid - DN_EXP_BLOCKS;
    const int m0 = (sid >> 3) * 64;
    n0 = (sid & 7) * 128;
    mguard = 64;
    K = SDIM;
    rowbase = m0;
    Ab = h_sh;
    Bb = sdwb + (size_t)n0 * SDIM;
  }

  const int srow = t >> 3;
  const int sc = (t & 7) ^ (srow & 7);
  const bf16* asrc[2];
#pragma unroll
  for (int i = 0; i < 2; ++i) {
    int rg = rowbase + i * 32 + srow;
    if (is_exp && rg > N_TOK * TOPK - 1) rg = N_TOK * TOPK - 1;
    asrc[i] = Ab + (size_t)rg * K + sc * 8;
  }
  const bf16* b0 = Bb + (size_t)srow * K + sc * 8;
  const int adst = t * 8;

#define ISSUE(k_, pb_)                                                        \
  do {                                                                        \
    _Pragma("unroll")                                                         \
    for (int i = 0; i < 2; ++i)                                               \
      gload16(asrc[i] + (k_), &sA[(pb_) * 4096 + adst + i * 2048]);           \
    _Pragma("unroll")                                                         \
    for (int i = 0; i < 4; ++i)                                               \
      gload16(b0 + (size_t)i * 32 * K + (k_),                                 \
              &sB[(pb_) * 8192 + adst + i * 2048]);                           \
  } while (0)

  const int wr = (wid >> 1) * 32, wc = (wid & 1) * 64;
  const int lrow = lane & 15, grp = lane >> 4;

  f32x4 acc[2][4];
#pragma unroll
  for (int m = 0; m < 2; ++m)
#pragma unroll
    for (int n = 0; n < 4; ++n)
#pragma unroll
      for (int i = 0; i < 4; ++i) acc[m][n][i] = 0.f;

  ISSUE(0, 0);
  __syncthreads();

  int p = 0;
  for (int k0 = 0; k0 < K; k0 += 64) {
    const int kn = k0 + 64;
    if (kn < K) ISSUE(kn, p ^ 1);
#pragma unroll
    for (int ks = 0; ks < 2; ++ks) {
      const int ch = ks * 4 + grp;
      bf16x8 av[2], bv[4];
#pragma unroll
      for (int m = 0; m < 2; ++m) {
        const int r = wr + m * 16 + lrow;
        av[m] = *(const bf16x8*)&sA[p * 4096 + r * 64 + ((ch ^ (r & 7)) << 3)];
      }
#pragma unroll
      for (int n = 0; n < 4; ++n) {
        const int r = wc + n * 16 + lrow;
        bv[n] = *(const bf16x8*)&sB[p * 8192 + r * 64 + ((ch ^ (r & 7)) << 3)];
      }
#pragma unroll
      for (int m = 0; m < 2; ++m)
#pragma unroll
        for (int n = 0; n < 4; ++n)
          acc[m][n] = __builtin_amdgcn_mfma_f32_16x16x32_bf16(av[m], bv[n], acc[m][n], 0, 0, 0);
    }
    __syncthreads();
    p ^= 1;
  }
#undef ISSUE

#pragma unroll
  for (int m = 0; m < 2; ++m) {
#pragma unroll
    for (int i = 0; i < 4; ++i) {
      const int rl = wr + m * 16 + grp * 4 + i;
      if (rl >= mguard) continue;
      if (is_exp) {
        const int row = rowbase + rl;
        const float scl = entry_gate[row];
        bf16* orow = out_e + (size_t)row * CDIM + n0;
#pragma unroll
        for (int n = 0; n < 4; ++n)
          orow[wc + n * 16 + lrow] = (bf16)(acc[m][n][i] * scl);
      } else {
        float* orow = out + (size_t)(rowbase + rl) * CDIM + n0;
#pragma unroll
        for (int n = 0; n < 4; ++n)
          orow[wc + n * 16 + lrow] = acc[m][n][i];
      }
    }
  }
}

// ---------------- combine ----------------
__global__ void combine_kernel(float* __restrict__ out,
                               const bf16* __restrict__ out_e,
                               const int* __restrict__ entry_pos) {
  int tid = blockIdx.x * blockDim.x + threadIdx.x;
  int n = tid >> 8;
  int c4 = tid & 255;
  int p0 = entry_pos[2 * n];
  int p1 = entry_pos[2 * n + 1];
  float4 v = ((const float4*)out)[tid];
  ushort4 a = *(const ushort4*)((const u16*)out_e + (size_t)p0 * CDIM + c4 * 4);
  ushort4 b = *(const ushort4*)((const u16*)out_e + (size_t)p1 * CDIM + c4 * 4);
  v.x += fromb(a.x) + fromb(b.x);
  v.y += fromb(a.y) + fromb(b.y);
  v.z += fromb(a.z) + fromb(b.z);
  v.w += fromb(a.w) + fromb(b.w);
  ((float4*)out)[tid] = v;
}

extern "C" void kernel_launch(void* const* d_in, const int* in_sizes, int n_in,
                              void* d_out, int out_size, void* d_ws, size_t ws_size,
                              hipStream_t stream) {
  const float* x   = (const float*)d_in[0];
  const float* rw  = (const float*)d_in[1];
  const float* guw = (const float*)d_in[2];
  const float* dw  = (const float*)d_in[3];
  const float* sgw = (const float*)d_in[4];
  const float* suw = (const float*)d_in[5];
  const float* sdw = (const float*)d_in[6];
  float* out = (float*)d_out;
  char* ws = (char*)d_ws;
  const size_t MB = 1048576;

  int*   sel         = (int*)(ws + 0);
  float* gatew       = (float*)(ws + 16384);
  int*   counts      = (int*)(ws + 32768);
  int*   offsets     = (int*)(ws + 32832);
  int*   cursor      = (int*)(ws + 32896);
  int*   ntiles      = (int*)(ws + 32960);
  int*   tab128      = (int*)(ws + 33024);
  int*   tab64       = (int*)(ws + 33280);
  int*   entry_token = (int*)(ws + 33664);
  float* entry_gate  = (float*)(ws + 50048);
  int*   entry_pos   = (int*)(ws + 66432);

  bf16* xb    = (bf16*)(ws + 82816);                 // 4 MB; later reused as sdw_b
  bf16* h_exp = (bf16*)(ws + 82816 + 4 * MB);        // 8 MB
  bf16* h_sh  = (bf16*)(ws + 82816 + 12 * MB);       // 8 MB
  bf16* sgw_b = (bf16*)(ws + 82816 + 20 * MB);       // 4 MB
  bf16* suw_b = (bf16*)(ws + 82816 + 24 * MB);       // 4 MB
  bf16* Wbig  = (bf16*)(ws + 82816 + 28 * MB);       // 64 MB: guw_b, then dw_b
  bf16* out_e = sgw_b;                               // alias (dead after gu)
  bf16* sdw_b = xb;                                  // alias (dead after gu)

  // routing + fused x conversion
  router_kernel<<<N_TOK, 64, 0, stream>>>(x, rw, xb, sel, gatew);
  scan_kernel<<<1, 256, 0, stream>>>(sel, counts, offsets, cursor, tab128, tab64, ntiles);
  scatter_kernel<<<16, 256, 0, stream>>>(sel, gatew, cursor, entry_token, entry_gate, entry_pos);

  // canonicalize gu-side weights
  convert_t<<<dim3(32, 16, NEXP), 256, 0, stream>>>(guw, Wbig, CDIM, 2 * HDIM);
  convert_plain<<<1024, 256, 0, stream>>>(sgw, sgw_b);
  convert_plain<<<1024, 256, 0, stream>>>(suw, suw_b);

  // gate+up + SwiGLU (expert + shared)
  gu6<<<GU_NWG, 256, 0, stream>>>(xb, Wbig, sgw_b, suw_b, h_exp, h_sh,
                                  counts, offsets, entry_token, tab128, ntiles);

  // canonicalize dn-side weights (into regions freed by gu)
  convert_t<<<dim3(16, 16, NEXP), 256, 0, stream>>>(dw, Wbig, HDIM, CDIM);
  convert_plain<<<1024, 256, 0, stream>>>(sdw, sdw_b);

  // down (expert + shared)
  dn6<<<DN_NWG, 256, 0, stream>>>(h_exp, h_sh, Wbig, sdw_b, entry_gate, out_e, out,
                                  counts, offsets, tab64, ntiles);

  // add gated expert contributions
  combine_kernel<<<(N_TOK * CDIM / 4) / 256, 256, 0, stream>>>(out, out_e, entry_pos);
}

// Round 11
// 192.130 us; speedup vs baseline: 1.7777x; 1.0494x over previous
//
#include <hip/hip_runtime.h>
#include <cstdint>

#define N_TOK 2048
#define CDIM  1024
#define NEXP  16
#define TOPK  2
#define HDIM  1024
#define SDIM  2048
#define ESLOT 48
#define ESLOT64 80
#define GU_EXP_BLOCKS (ESLOT * 16)              // 768
#define GU_SH_BLOCKS  (16 * 32)                 // 512
#define GU_NWG (GU_EXP_BLOCKS + GU_SH_BLOCKS)   // 1280
#define DN_EXP_BLOCKS (ESLOT64 * 8)             // 640
#define DN_SH_BLOCKS  (32 * 8)                  // 256
#define DN_NWG (DN_EXP_BLOCKS + DN_SH_BLOCKS)   // 896

typedef __bf16 bf16;
typedef __bf16 bf16x8 __attribute__((ext_vector_type(8)));
typedef float  f32x4  __attribute__((ext_vector_type(4)));
typedef unsigned int u32;
typedef unsigned short u16;

typedef __attribute__((address_space(3))) uint32_t lds_u32_t;
typedef __attribute__((address_space(1))) uint32_t glb_u32_t;

__device__ __forceinline__ void gload16(const void* g, void* l) {
  __builtin_amdgcn_global_load_lds((const glb_u32_t*)(uintptr_t)g,
                                   (lds_u32_t*)(uintptr_t)l, 16, 0, 0);
}
__device__ __forceinline__ float fromb(u16 s) {
  union { float f; u32 u; } z; z.u = ((u32)s) << 16; return z.f;
}
__device__ __forceinline__ int xcd_swz(int bid, int nwg) {
  return (bid & 7) * (nwg >> 3) + (bid >> 3);
}
#define SBAR0() __builtin_amdgcn_sched_barrier(0)
#define WAIT_VM(N) do { asm volatile("s_waitcnt vmcnt(" #N ")" ::: "memory"); \
                        SBAR0(); } while (0)

// ---------------- weight canonicalization ----------------
__global__ void convert_plain(const float* __restrict__ s, bf16* __restrict__ d) {
  int i = (blockIdx.x * 256 + threadIdx.x) * 8;
  float4 f0 = *(const float4*)(s + i);
  float4 f1 = *(const float4*)(s + i + 4);
  bf16x8 v;
  v[0]=(bf16)f0.x; v[1]=(bf16)f0.y; v[2]=(bf16)f0.z; v[3]=(bf16)f0.w;
  v[4]=(bf16)f1.x; v[5]=(bf16)f1.y; v[6]=(bf16)f1.z; v[7]=(bf16)f1.w;
  *(bf16x8*)(d + i) = v;
}

// transpose-convert: src [E][K][N] fp32 -> dst [E][N][K] bf16 (64x64 tiles)
__global__ __launch_bounds__(256)
void convert_t(const float* __restrict__ src, bf16* __restrict__ dst, int K, int N) {
  __shared__ float ld[64 * 68];
  const int e = blockIdx.z;
  const int n0 = blockIdx.x * 64, k0 = blockIdx.y * 64;
  const float* s = src + (size_t)e * K * N;
  bf16* d = dst + (size_t)e * N * K;
  const int t = threadIdx.x;
  const int kk = t >> 4, c4 = (t & 15) * 4;
#pragma unroll
  for (int q = 0; q < 4; ++q) {
    float4 f = *(const float4*)(s + (size_t)(k0 + kk + q * 16) * N + n0 + c4);
    float* lp = &ld[(kk + q * 16) * 68 + c4];
    lp[0] = f.x; lp[1] = f.y; lp[2] = f.z; lp[3] = f.w;
  }
  __syncthreads();
  const int nn = t >> 2, kc = (t & 3) * 16;
  bf16x8 v0, v1;
#pragma unroll
  for (int j = 0; j < 8; ++j) {
    v0[j] = (bf16)ld[(kc + j) * 68 + nn];
    v1[j] = (bf16)ld[(kc + 8 + j) * 68 + nn];
  }
  bf16* dp = d + (size_t)(n0 + nn) * K + k0 + kc;
  *(bf16x8*)dp = v0;
  *(bf16x8*)(dp + 8) = v1;
}

// ---------------- router (fused x->bf16 conversion; no atomics) ----------------
__global__ void router_kernel(const float* __restrict__ x,
                              const float* __restrict__ rw,
                              bf16* __restrict__ xb,
                              int* __restrict__ sel,
                              float* __restrict__ gatew) {
  int n = blockIdx.x;
  int lane = threadIdx.x;
  const float* xr = x + (size_t)n * CDIM;
  float xv[16];
#pragma unroll
  for (int q = 0; q < 4; ++q) {
    float4 f = *(const float4*)(xr + lane * 16 + q * 4);
    xv[q * 4 + 0] = f.x; xv[q * 4 + 1] = f.y; xv[q * 4 + 2] = f.z; xv[q * 4 + 3] = f.w;
  }
  bf16x8 v0, v1;
#pragma unroll
  for (int j = 0; j < 8; ++j) { v0[j] = (bf16)xv[j]; v1[j] = (bf16)xv[8 + j]; }
  bf16* xo = xb + (size_t)n * CDIM + lane * 16;
  *(bf16x8*)xo = v0;
  *(bf16x8*)(xo + 8) = v1;
  float acc[NEXP];
#pragma unroll
  for (int e = 0; e < NEXP; ++e) {
    float a = 0.f;
    const float* rwe = rw + e * CDIM + lane * 16;
#pragma unroll
    for (int j = 0; j < 16; ++j) a += xv[j] * rwe[j];
    acc[e] = a;
  }
#pragma unroll
  for (int off = 32; off > 0; off >>= 1) {
#pragma unroll
    for (int e = 0; e < NEXP; ++e) acc[e] += __shfl_xor(acc[e], off, 64);
  }
  if (lane == 0) {
    int i0 = 0; float v0_ = acc[0];
#pragma unroll
    for (int e = 1; e < NEXP; ++e) if (acc[e] > v0_) { v0_ = acc[e]; i0 = e; }
    int i1 = (i0 == 0) ? 1 : 0; float v1_ = acc[i1];
#pragma unroll
    for (int e = 0; e < NEXP; ++e) if (e != i0 && acc[e] > v1_) { v1_ = acc[e]; i1 = e; }
    sel[2 * n] = i0; sel[2 * n + 1] = i1;
    gatew[2 * n]     = 1.f / (1.f + expf(-v0_));
    gatew[2 * n + 1] = 1.f / (1.f + expf(-v1_));
  }
}

__global__ void scan_kernel(const int* __restrict__ sel,
                            int* __restrict__ counts,
                            int* __restrict__ offsets,
                            int* __restrict__ cursor,
                            int* __restrict__ tab128,
                            int* __restrict__ tab64,
                            int* __restrict__ ntiles) {
  __shared__ int hist[NEXP];
  const int t = threadIdx.x;
  if (t < NEXP) hist[t] = 0;
  __syncthreads();
  for (int i = t; i < N_TOK * TOPK; i += 256) atomicAdd(&hist[sel[i]], 1);
  __syncthreads();
  if (t == 0) {
    int s = 0, a = 0, b = 0;
    for (int e = 0; e < NEXP; ++e) {
      int c = hist[e];
      counts[e] = c; offsets[e] = s; cursor[e] = s;
      for (int m0 = 0; m0 < c; m0 += 128) tab128[a++] = (e << 16) | m0;
      for (int m0 = 0; m0 < c; m0 += 64)  tab64[b++]  = (e << 16) | m0;
      s += c;
    }
    ntiles[0] = a; ntiles[1] = b;
  }
}

__global__ void scatter_kernel(const int* __restrict__ sel,
                               const float* __restrict__ gatew,
                               int* __restrict__ cursor,
                               int* __restrict__ entry_token,
                               float* __restrict__ entry_gate,
                               int* __restrict__ entry_pos) {
  int t = blockIdx.x * blockDim.x + threadIdx.x;
  if (t >= N_TOK * TOPK) return;
  int e = sel[t];
  int pos = atomicAdd(&cursor[e], 1);
  entry_token[pos] = t >> 1;
  entry_gate[pos] = gatew[t];
  entry_pos[t] = pos;
}

// ================= GU: gate+up GEMM, counted-vmcnt deep pipeline ==============
// Tile 128m x 64h dual-B, BK=64. A: dbuf (1-ahead). B: 3-buf (2-ahead).
// Barrier = s_waitcnt vmcnt(4) + s_barrier: B(k+2) loads stay in flight.
__global__ __launch_bounds__(256, 2)
void gu7(const bf16* __restrict__ xb,
         const bf16* __restrict__ guwb,    // [E][2048][1024]
         const bf16* __restrict__ sgwb,
         const bf16* __restrict__ suwb,
         bf16* __restrict__ h_exp,
         bf16* __restrict__ h_sh,
         const int* __restrict__ counts,
         const int* __restrict__ offsets,
         const int* __restrict__ entry_token,
         const int* __restrict__ tab128,
         const int* __restrict__ ntiles) {
  __shared__ __align__(16) bf16 sA[2 * 8192];    // 2 x 128x64 (32 KB)
  __shared__ __align__(16) bf16 sBg[3 * 4096];   // 3 x 64x64 (24 KB)
  __shared__ __align__(16) bf16 sBu[3 * 4096];   // 24 KB  -> 80 KB total

  const int bid = xcd_swz(blockIdx.x, GU_NWG);
  const int t = threadIdx.x;
  const bool is_exp = bid < GU_EXP_BLOCKS;
  const int wid = t >> 6, lane = t & 63;

  int n0, mguard;
  bf16* hbase; int hstride;
  const bf16 *Bg, *Bu;
  const int srow = t >> 3;
  const int sc = (t & 7) ^ (srow & 7);
  const bf16* asrc[4];

  if (is_exp) {
    const int slot = bid >> 4;
    if (slot >= ntiles[0]) return;
    const int packed = tab128[slot];
    const int e = packed >> 16;
    const int m0 = packed & 0xffff;
    const int cnt = counts[e];
    const int base = offsets[e];
    n0 = (bid & 15) * 64;
    mguard = cnt - m0;
#pragma unroll
    for (int i = 0; i < 4; ++i) {
      int r = m0 + i * 32 + srow;
      int tok = entry_token[base + ((r < cnt) ? r : (cnt - 1))];
      asrc[i] = xb + (size_t)tok * CDIM + sc * 8;
    }
    const bf16* we = guwb + (size_t)e * (2 * HDIM) * CDIM;
    Bg = we + (size_t)n0 * CDIM;
    Bu = we + (size_t)(HDIM + n0) * CDIM;
    hbase = h_exp + (size_t)(base + m0) * HDIM + n0;
    hstride = HDIM;
  } else {
    const int sid = bid - GU_EXP_BLOCKS;
    const int m0 = (sid >> 5) * 128;
    n0 = (sid & 31) * 64;
    mguard = 128;
#pragma unroll
    for (int i = 0; i < 4; ++i)
      asrc[i] = xb + (size_t)(m0 + i * 32 + srow) * CDIM + sc * 8;
    Bg = sgwb + (size_t)n0 * CDIM;
    Bu = suwb + (size_t)n0 * CDIM;
    hbase = h_sh + (size_t)m0 * SDIM + n0;
    hstride = SDIM;
  }

  const bf16* bg0 = Bg + (size_t)srow * CDIM + sc * 8;
  const bf16* bu0 = Bu + (size_t)srow * CDIM + sc * 8;
  const int adst = t * 8;

#define ISSUE_A(k_, ab_)                                                      \
  do {                                                                        \
    _Pragma("unroll")                                                         \
    for (int i = 0; i < 4; ++i)                                               \
      gload16(asrc[i] + (k_), &sA[(ab_) * 8192 + adst + i * 2048]);           \
  } while (0)
#define ISSUE_B(k_, bo_)                                                      \
  do {                                                                        \
    _Pragma("unroll")                                                         \
    for (int i = 0; i < 2; ++i) {                                             \
      gload16(bg0 + (size_t)i * 32 * CDIM + (k_), &sBg[(bo_) + adst + i * 2048]); \
      gload16(bu0 + (size_t)i * 32 * CDIM + (k_), &sBu[(bo_) + adst + i * 2048]); \
    }                                                                         \
  } while (0)

  const int wr = (wid >> 1) * 64, wc = (wid & 1) * 32;
  const int lrow = lane & 15, grp = lane >> 4;

  f32x4 ag[4][2], au[4][2];
#pragma unroll
  for (int m = 0; m < 4; ++m)
#pragma unroll
    for (int n = 0; n < 2; ++n)
#pragma unroll
      for (int i = 0; i < 4; ++i) { ag[m][n][i] = 0.f; au[m][n][i] = 0.f; }

#define COMPUTE(ab_, bo_)                                                     \
  do {                                                                        \
    _Pragma("unroll")                                                         \
    for (int ks = 0; ks < 2; ++ks) {                                          \
      const int ch = ks * 4 + grp;                                            \
      bf16x8 av[4], bg[2], bu[2];                                             \
      _Pragma("unroll")                                                       \
      for (int m = 0; m < 4; ++m) {                                           \
        const int r = wr + m * 16 + lrow;                                     \
        av[m] = *(const bf16x8*)&sA[(ab_) * 8192 + r * 64 + ((ch ^ (r & 7)) << 3)]; \
      }                                                                       \
      _Pragma("unroll")                                                       \
      for (int n = 0; n < 2; ++n) {                                           \
        const int r = wc + n * 16 + lrow;                                     \
        bg[n] = *(const bf16x8*)&sBg[(bo_) + r * 64 + ((ch ^ (r & 7)) << 3)]; \
        bu[n] = *(const bf16x8*)&sBu[(bo_) + r * 64 + ((ch ^ (r & 7)) << 3)]; \
      }                                                                       \
      _Pragma("unroll")                                                       \
      for (int m = 0; m < 4; ++m)                                             \
        _Pragma("unroll")                                                     \
        for (int n = 0; n < 2; ++n) {                                         \
          ag[m][n] = __builtin_amdgcn_mfma_f32_16x16x32_bf16(av[m], bg[n], ag[m][n], 0, 0, 0); \
          au[m][n] = __builtin_amdgcn_mfma_f32_16x16x32_bf16(av[m], bu[n], au[m][n], 0, 0, 0); \
        }                                                                     \
    }                                                                         \
  } while (0)

  // prologue: A(0),B(0) then B(1); wait so only B(1) stays in flight
  ISSUE_A(0, 0);
  ISSUE_B(0, 0);
  SBAR0();
  ISSUE_B(64, 4096);
  SBAR0();
  WAIT_VM(4);
  __builtin_amdgcn_s_barrier();

  int bb0 = 0, bb1 = 4096, bb2 = 8192;
  // main: k = 0..13  (16 K-steps total)
  for (int k = 0; k < 14; ++k) {
    ISSUE_A((k + 1) * 64, (k + 1) & 1);
    SBAR0();
    ISSUE_B((k + 2) * 64, bb2);
    SBAR0();
    COMPUTE(k & 1, bb0);
    WAIT_VM(4);               // A(k+1)+B(k+1) done; B(k+2) stays in flight
    __builtin_amdgcn_s_barrier();
    int tmp = bb0; bb0 = bb1; bb1 = bb2; bb2 = tmp;
  }
  // k = 14
  ISSUE_A(15 * 64, 1);
  SBAR0();
  COMPUTE(0, bb0);
  WAIT_VM(0);
  __builtin_amdgcn_s_barrier();
  { int tmp = bb0; bb0 = bb1; bb1 = bb2; bb2 = tmp; }
  // k = 15
  COMPUTE(1, bb0);
#undef ISSUE_A
#undef ISSUE_B
#undef COMPUTE

  // SwiGLU epilogue (C/D: col=lane&15, row=grp*4+i)
#pragma unroll
  for (int m = 0; m < 4; ++m) {
#pragma unroll
    for (int i = 0; i < 4; ++i) {
      const int rl = wr + m * 16 + grp * 4 + i;
      if (rl >= mguard) continue;
      bf16* orow = hbase + (size_t)rl * hstride;
#pragma unroll
      for (int n = 0; n < 2; ++n) {
        const float g = ag[m][n][i];
        const float u = au[m][n][i];
        orow[wc + n * 16 + lrow] = (bf16)(g * u * __builtin_amdgcn_rcpf(1.f + __expf(-g)));
      }
    }
  }
}

// ================= DOWN GEMM, counted-vmcnt deep pipeline =====================
// Tile 64m x 128n, BK=64. A: dbuf (1-ahead). B: 3-buf (2-ahead). vmcnt(4).
__global__ __launch_bounds__(256, 2)
void dn7(const bf16* __restrict__ h_exp,
         const bf16* __restrict__ h_sh,
         const bf16* __restrict__ dwb,    // [E][1024][1024]
         const bf16* __restrict__ sdwb,   // [1024][2048]
         const float* __restrict__ entry_gate,
         bf16* __restrict__ out_e,
         float* __restrict__ out,
         const int* __restrict__ counts,
         const int* __restrict__ offsets,
         const int* __restrict__ tab64,
         const int* __restrict__ ntiles) {
  __shared__ __align__(16) bf16 sA[2 * 4096];    // 2 x 64x64 (16 KB)
  __shared__ __align__(16) bf16 sB[3 * 8192];    // 3 x 128x64 (48 KB)

  const int bid = xcd_swz(blockIdx.x, DN_NWG);
  const int t = threadIdx.x;
  const bool is_exp = bid < DN_EXP_BLOCKS;
  const int wid = t >> 6, lane = t & 63;

  int n0, mguard, K, rowbase, NK;
  const bf16* Ab;
  const bf16* Bb;

  if (is_exp) {
    const int slot = bid >> 3;
    if (slot >= ntiles[1]) return;
    const int packed = tab64[slot];
    const int e = packed >> 16;
    const int m0 = packed & 0xffff;
    const int cnt = counts[e];
    n0 = (bid & 7) * 128;
    mguard = cnt - m0;
    K = HDIM; NK = HDIM / 64;
    rowbase = offsets[e] + m0;
    Ab = h_exp;
    Bb = dwb + (size_t)e * CDIM * HDIM + (size_t)n0 * HDIM;
  } else {
    const int sid = bid - DN_EXP_BLOCKS;
    const int m0 = (sid >> 3) * 64;
    n0 = (sid & 7) * 128;
    mguard = 64;
    K = SDIM; NK = SDIM / 64;
    rowbase = m0;
    Ab = h_sh;
    Bb = sdwb + (size_t)n0 * SDIM;
  }

  const int srow = t >> 3;
  const int sc = (t & 7) ^ (srow & 7);
  const bf16* asrc[2];
#pragma unroll
  for (int i = 0; i < 2; ++i) {
    int rg = rowbase + i * 32 + srow;
    if (is_exp && rg > N_TOK * TOPK - 1) rg = N_TOK * TOPK - 1;
    asrc[i] = Ab + (size_t)rg * K + sc * 8;
  }
  const bf16* b0 = Bb + (size_t)srow * K + sc * 8;
  const int adst = t * 8;

#define ISSUE_A(k_, ab_)                                                      \
  do {                                                                        \
    _Pragma("unroll")                                                         \
    for (int i = 0; i < 2; ++i)                                               \
      gload16(asrc[i] + (k_), &sA[(ab_) * 4096 + adst + i * 2048]);           \
  } while (0)
#define ISSUE_B(k_, bo_)                                                      \
  do {                                                                        \
    _Pragma("unroll")                                                         \
    for (int i = 0; i < 4; ++i)                                               \
      gload16(b0 + (size_t)i * 32 * K + (k_), &sB[(bo_) + adst + i * 2048]);  \
  } while (0)

  const int wr = (wid >> 1) * 32, wc = (wid & 1) * 64;
  const int lrow = lane & 15, grp = lane >> 4;

  f32x4 acc[2][4];
#pragma unroll
  for (int m = 0; m < 2; ++m)
#pragma unroll
    for (int n = 0; n < 4; ++n)
#pragma unroll
      for (int i = 0; i < 4; ++i) acc[m][n][i] = 0.f;

#define COMPUTE(ab_, bo_)                                                     \
  do {                                                                        \
    _Pragma("unroll")                                                         \
    for (int ks = 0; ks < 2; ++ks) {                                          \
      const int ch = ks * 4 + grp;                                            \
      bf16x8 av[2], bv[4];                                                    \
      _Pragma("unroll")                                                       \
      for (int m = 0; m < 2; ++m) {                                           \
        const int r = wr + m * 16 + lrow;                                     \
        av[m] = *(const bf16x8*)&sA[(ab_) * 4096 + r * 64 + ((ch ^ (r & 7)) << 3)]; \
      }                                                                       \
      _Pragma("unroll")                                                       \
      for (int n = 0; n < 4; ++n) {                                           \
        const int r = wc + n * 16 + lrow;                                     \
        bv[n] = *(const bf16x8*)&sB[(bo_) + r * 64 + ((ch ^ (r & 7)) << 3)];  \
      }                                                                       \
      _Pragma("unroll")                                                       \
      for (int m = 0; m < 2; ++m)                                             \
        _Pragma("unroll")                                                     \
        for (int n = 0; n < 4; ++n)                                           \
          acc[m][n] = __builtin_amdgcn_mfma_f32_16x16x32_bf16(av[m], bv[n], acc[m][n], 0, 0, 0); \
    }                                                                         \
  } while (0)

  ISSUE_A(0, 0);
  ISSUE_B(0, 0);
  SBAR0();
  ISSUE_B(64, 8192);
  SBAR0();
  WAIT_VM(4);
  __builtin_amdgcn_s_barrier();

  int bb0 = 0, bb1 = 8192, bb2 = 16384;
  for (int k = 0; k < NK - 2; ++k) {
    ISSUE_A((k + 1) * 64, (k + 1) & 1);
    SBAR0();
    ISSUE_B((k + 2) * 64, bb2);
    SBAR0();
    COMPUTE(k & 1, bb0);
    WAIT_VM(4);
    __builtin_amdgcn_s_barrier();
    int tmp = bb0; bb0 = bb1; bb1 = bb2; bb2 = tmp;
  }
  // k = NK-2
  ISSUE_A((NK - 1) * 64, (NK - 1) & 1);
  SBAR0();
  COMPUTE((NK - 2) & 1, bb0);
  WAIT_VM(0);
  __builtin_amdgcn_s_barrier();
  { int tmp = bb0; bb0 = bb1; bb1 = bb2; bb2 = tmp; }
  // k = NK-1
  COMPUTE((NK - 1) & 1, bb0);
#undef ISSUE_A
#undef ISSUE_B
#undef COMPUTE

#pragma unroll
  for (int m = 0; m < 2; ++m) {
#pragma unroll
    for (int i = 0; i < 4; ++i) {
      const int rl = wr + m * 16 + grp * 4 + i;
      if (rl >= mguard) continue;
      if (is_exp) {
        const int row = rowbase + rl;
        const float scl = entry_gate[row];
        bf16* orow = out_e + (size_t)row * CDIM + n0;
#pragma unroll
        for (int n = 0; n < 4; ++n)
          orow[wc + n * 16 + lrow] = (bf16)(acc[m][n][i] * scl);
      } else {
        float* orow = out + (size_t)(rowbase + rl) * CDIM + n0;
#pragma unroll
        for (int n = 0; n < 4; ++n)
          orow[wc + n * 16 + lrow] = acc[m][n][i];
      }
    }
  }
}

// ---------------- combine ----------------
__global__ void combine_kernel(float* __restrict__ out,
                               const bf16* __restrict__ out_e,
                               const int* __restrict__ entry_pos) {
  int tid = blockIdx.x * blockDim.x + threadIdx.x;
  int n = tid >> 8;
  int c4 = tid & 255;
  int p0 = entry_pos[2 * n];
  int p1 = entry_pos[2 * n + 1];
  float4 v = ((const float4*)out)[tid];
  ushort4 a = *(const ushort4*)((const u16*)out_e + (size_t)p0 * CDIM + c4 * 4);
  ushort4 b = *(const ushort4*)((const u16*)out_e + (size_t)p1 * CDIM + c4 * 4);
  v.x += fromb(a.x) + fromb(b.x);
  v.y += fromb(a.y) + fromb(b.y);
  v.z += fromb(a.z) + fromb(b.z);
  v.w += fromb(a.w) + fromb(b.w);
  ((float4*)out)[tid] = v;
}

extern "C" void kernel_launch(void* const* d_in, const int* in_sizes, int n_in,
                              void* d_out, int out_size, void* d_ws, size_t ws_size,
                              hipStream_t stream) {
  const float* x   = (const float*)d_in[0];
  const float* rw  = (const float*)d_in[1];
  const float* guw = (const float*)d_in[2];
  const float* dw  = (const float*)d_in[3];
  const float* sgw = (const float*)d_in[4];
  const float* suw = (const float*)d_in[5];
  const float* sdw = (const float*)d_in[6];
  float* out = (float*)d_out;
  char* ws = (char*)d_ws;
  const size_t MB = 1048576;

  int*   sel         = (int*)(ws + 0);
  float* gatew       = (float*)(ws + 16384);
  int*   counts      = (int*)(ws + 32768);
  int*   offsets     = (int*)(ws + 32832);
  int*   cursor      = (int*)(ws + 32896);
  int*   ntiles      = (int*)(ws + 32960);
  int*   tab128      = (int*)(ws + 33024);
  int*   tab64       = (int*)(ws + 33280);
  int*   entry_token = (int*)(ws + 33664);
  float* entry_gate  = (float*)(ws + 50048);
  int*   entry_pos   = (int*)(ws + 66432);

  bf16* xb    = (bf16*)(ws + 82816);                 // 4 MB; later reused as sdw_b
  bf16* h_exp = (bf16*)(ws + 82816 + 4 * MB);        // 8 MB
  bf16* h_sh  = (bf16*)(ws + 82816 + 12 * MB);       // 8 MB
  bf16* sgw_b = (bf16*)(ws + 82816 + 20 * MB);       // 4 MB
  bf16* suw_b = (bf16*)(ws + 82816 + 24 * MB);       // 4 MB
  bf16* Wbig  = (bf16*)(ws + 82816 + 28 * MB);       // 64 MB: guw_b, then dw_b
  bf16* out_e = sgw_b;                               // alias (dead after gu)
  bf16* sdw_b = xb;                                  // alias (dead after gu)

  // routing + fused x conversion
  router_kernel<<<N_TOK, 64, 0, stream>>>(x, rw, xb, sel, gatew);
  scan_kernel<<<1, 256, 0, stream>>>(sel, counts, offsets, cursor, tab128, tab64, ntiles);
  scatter_kernel<<<16, 256, 0, stream>>>(sel, gatew, cursor, entry_token, entry_gate, entry_pos);

  // canonicalize gu-side weights
  convert_t<<<dim3(32, 16, NEXP), 256, 0, stream>>>(guw, Wbig, CDIM, 2 * HDIM);
  convert_plain<<<1024, 256, 0, stream>>>(sgw, sgw_b);
  convert_plain<<<1024, 256, 0, stream>>>(suw, suw_b);

  // gate+up + SwiGLU (expert + shared)
  gu7<<<GU_NWG, 256, 0, stream>>>(xb, Wbig, sgw_b, suw_b, h_exp, h_sh,
                                  counts, offsets, entry_token, tab128, ntiles);

  // canonicalize dn-side weights (into regions freed by gu)
  convert_t<<<dim3(16, 16, NEXP), 256, 0, stream>>>(dw, Wbig, HDIM, CDIM);
  convert_plain<<<1024, 256, 0, stream>>>(sdw, sdw_b);

  // down (expert + shared)
  dn7<<<DN_NWG, 256, 0, stream>>>(h_exp, h_sh, Wbig, sdw_b, entry_gate, out_e, out,
                                  counts, offsets, tab64, ntiles);

  // add gated expert contributions
  combine_kernel<<<(N_TOK * CDIM / 4) / 256, 256, 0, stream>>>(out, out_e, entry_pos);
}